// Round 9
// baseline (258.926 us; speedup 1.0000x reference)
//
#include <hip/hip_runtime.h>
#include <math.h>

typedef __bf16 bf16x8 __attribute__((ext_vector_type(8)));
typedef float f32x4 __attribute__((ext_vector_type(4)));

#define EPSV 1e-5f

__device__ __forceinline__ unsigned fkey(float f) {
  unsigned b = __float_as_uint(f);
  return (b & 0x80000000u) ? ~b : (b | 0x80000000u);
}
__device__ __forceinline__ float funkey(unsigned k) {
  return __uint_as_float((k & 0x80000000u) ? (k & 0x7fffffffu) : ~k);
}

// ---- single-pass norm: block owns p-tile x all C; stats in regs+LDS, then
// apply+store bf16 [N][Ppad][C]. Pad blocks (y>=NWORK) zero the pad rows. ----
// grid (1, 100, 8): z>>2 = layer, z&3 = n.
__global__ __launch_bounds__(256) void norm_kernel(
    const float* __restrict__ g3, const float* __restrict__ t3,
    __bf16* __restrict__ G3, __bf16* __restrict__ T3,
    const float* __restrict__ g4, const float* __restrict__ t4,
    __bf16* __restrict__ G4, __bf16* __restrict__ T4)
{
  int lay = blockIdx.z >> 2, n = blockIdx.z & 3;
  const float *gen, *tar; __bf16 *Gh, *Th; int C, P, Ppad, PT, NWORK, NTOT, NG;
  if (lay == 0) { gen = g3; tar = t3; Gh = G3; Th = T3; C = 256; P = 3136; Ppad = 3200; PT = 32; NWORK = 98; NTOT = 100; NG = 8; }
  else          { gen = g4; tar = t4; Gh = G4; Th = T4; C = 512; P = 784;  Ppad = 896;  PT = 16; NWORK = 49; NTOT = 56;  NG = 16; }
  if (blockIdx.y >= (unsigned)NTOT) return;
  int pl, cg;
  if (lay == 0) { pl = threadIdx.x & 31; cg = threadIdx.x >> 5; }
  else          { pl = threadIdx.x & 15; cg = threadIdx.x >> 4; }
  int c0 = cg * 32;

  if (blockIdx.y >= (unsigned)NWORK) {  // zero pad rows
    int p = P + (blockIdx.y - NWORK) * PT + pl;
    if (p < Ppad) {
      __bf16* tp = Th + ((size_t)n * Ppad + p) * C + c0;
      __bf16* gp = Gh + ((size_t)n * Ppad + p) * C + c0;
      bf16x8 z;
      for (int j = 0; j < 8; j++) z[j] = (__bf16)0.f;
      for (int j = 0; j < 32; j += 8) { *(bf16x8*)(tp + j) = z; *(bf16x8*)(gp + j) = z; }
    }
    return;
  }

  int p = blockIdx.y * PT + pl;
  const float* tb = tar + (size_t)n * C * P + (size_t)c0 * P + p;
  const float* gb = gen + (size_t)n * C * P + (size_t)c0 * P + p;
  float tv[32], gv[32];
  float st = 0.f, sst = 0.f, sg = 0.f, ssg = 0.f;
#pragma unroll
  for (int j = 0; j < 32; j++) {
    tv[j] = tb[(size_t)j * P];
    gv[j] = gb[(size_t)j * P];
  }
#pragma unroll
  for (int j = 0; j < 32; j++) {
    st += tv[j]; sst += tv[j] * tv[j];
    sg += gv[j]; ssg += gv[j] * gv[j];
  }
  __shared__ f32x4 red[16][32];
  red[cg][pl] = f32x4{st, sst, sg, ssg};
  __syncthreads();
  for (int h = NG >> 1; h > 0; h >>= 1) {
    if (cg < h) {
      f32x4 a = red[cg][pl], b = red[cg + h][pl];
      red[cg][pl] = f32x4{a[0] + b[0], a[1] + b[1], a[2] + b[2], a[3] + b[3]};
    }
    __syncthreads();
  }
  f32x4 s = red[0][pl];
  float m = s[0] / (float)C;
  float vt = s[1] - s[0] * s[0] / (float)C;
  float vg = s[3] - 2.f * m * s[2] + (float)C * m * m;
  float it = rsqrtf(fmaxf(vt, 1e-30f));
  float ig = rsqrtf(fmaxf(vg, 1e-30f));
  __bf16* tp = Th + ((size_t)n * Ppad + p) * C + c0;
  __bf16* gp = Gh + ((size_t)n * Ppad + p) * C + c0;
#pragma unroll
  for (int j0 = 0; j0 < 32; j0 += 8) {
    bf16x8 to, go;
    for (int j = 0; j < 8; j++) {
      to[j] = (__bf16)((tv[j0 + j] - m) * it);
      go[j] = (__bf16)((gv[j0 + j] - m) * ig);
    }
    *(bf16x8*)(tp + j0) = to;
    *(bf16x8*)(gp + j0) = go;
  }
}

// ---- GEMM: 128x128 tile, NO-LDS direct-fragment loads (both operands K-
// contiguous -> MFMA A/B fragment == 16-B global load). Zero barriers in the
// K-loop; register double-buffered fragments; LDS only for the coalesced
// non-temporal epilogue. ----
__global__ __launch_bounds__(256, 3) void gemm_kernel(
    const __bf16* __restrict__ A3, const __bf16* __restrict__ B3,
    __bf16* __restrict__ So3, unsigned* __restrict__ dk3,
    const __bf16* __restrict__ A4, const __bf16* __restrict__ B4,
    __bf16* __restrict__ So4, unsigned* __restrict__ dk4)
{
  __shared__ __attribute__((aligned(16))) char smem[37888];  // 128 x 296 B epilogue bounce

  int id = blockIdx.x;
  const __bf16 *A, *B; __bf16* S; unsigned* dk;
  int C, Ppad, Qpad, Preal, NT, n, t;
  if (id < 2500) {
    n = id / 625; t = id - n * 625;
    A = A3; B = B3; S = So3; dk = dk3; C = 256; Ppad = 3200; Qpad = 3200; Preal = 3136; NT = 25;
  } else {
    id -= 2500;
    n = id / 49; t = id - n * 49;
    A = A4; B = B4; S = So4; dk = dk4; C = 512; Ppad = 896;  Qpad = 896;  Preal = 784;  NT = 7;
  }
  // band swizzle: bands of 8 p-tiles, q fastest within a band
  int bpb = NT * 8;
  int b = t / bpb, r = t - b * bpb;
  int rem = NT - b * 8;
  int h = rem < 8 ? rem : 8;
  int pt = b * 8 + r % h, qt = r / h;
  int p0 = pt * 128, q0 = qt * 128;

  int tid = threadIdx.x;
  int w = tid >> 6, lane = tid & 63;
  int lm = lane & 15, lq = lane >> 4;
  int wrow = (w >> 1) * 64, wcol = (w & 1) * 64;

  // direct fragment pointers: A[m=lm][k=lq*8+j] is 16 contiguous bytes
  const __bf16* aBase = A + ((size_t)n * Ppad + p0 + wrow + lm) * C + lq * 8;
  const __bf16* bBase = B + ((size_t)n * Qpad + q0 + wcol + lm) * C + lq * 8;
  size_t rstep = (size_t)16 * C;  // 16 rows

  f32x4 acc[4][4];
  for (int i = 0; i < 4; i++)
    for (int j = 0; j < 4; j++)
      acc[i][j] = f32x4{0.f, 0.f, 0.f, 0.f};

  bf16x8 a0[4], b0[4], a1[4], b1[4];
  auto loadf = [&](int k, bf16x8* af, bf16x8* bf) {
#pragma unroll
    for (int i = 0; i < 4; i++) af[i] = *(const bf16x8*)(aBase + (size_t)i * rstep + k);
#pragma unroll
    for (int j = 0; j < 4; j++) bf[j] = *(const bf16x8*)(bBase + (size_t)j * rstep + k);
  };
  auto domfma = [&](bf16x8* af, bf16x8* bf) {
#pragma unroll
    for (int i = 0; i < 4; i++)
#pragma unroll
      for (int j = 0; j < 4; j++)
        acc[i][j] = __builtin_amdgcn_mfma_f32_16x16x32_bf16(af[i], bf[j], acc[i][j], 0, 0, 0);
  };

  int nk = C >> 5;  // 8 or 16 (even)
  loadf(0, a0, b0);
  int k = 32;
  for (int it = 0; it < (nk >> 1) - 1; it++) {
    loadf(k, a1, b1); domfma(a0, b0); k += 32;
    loadf(k, a0, b0); domfma(a1, b1); k += 32;
  }
  loadf(k, a1, b1);
  domfma(a0, b0);
  domfma(a1, b1);

  // colmax from registers (D: row = lq*4+ri, col = lm within 16x16 sub-tile)
  float cm[4] = {-INFINITY, -INFINITY, -INFINITY, -INFINITY};
  for (int i = 0; i < 4; i++)
    for (int j = 0; j < 4; j++)
      for (int ri = 0; ri < 4; ri++) {
        int pr = p0 + wrow + i * 16 + lq * 4 + ri;
        if (pr < Preal) cm[j] = fmaxf(cm[j], (float)(__bf16)acc[i][j][ri]);
      }

  // epilogue: bounce through LDS (296-B pitch, conflict-free), then
  // fully-coalesced non-temporal bf16x8 row stores.
  for (int i = 0; i < 4; i++) {
    for (int j = 0; j < 4; j++) {
      int row = wrow + i * 16 + lq * 4;
      int col = wcol + j * 16 + lm;
      for (int ri = 0; ri < 4; ri++)
        *(__bf16*)(smem + (row + ri) * 296 + col * 2) = (__bf16)acc[i][j][ri];
    }
  }
  __syncthreads();
  __bf16* Sb = S + (size_t)n * Ppad * Qpad;
  int rr = tid >> 4, cc8 = (tid & 15) * 8;
  for (int r8 = 0; r8 < 8; r8++) {
    int row = r8 * 16 + rr;
    bf16x8 v = *(const bf16x8*)(smem + row * 296 + cc8 * 2);
    __builtin_nontemporal_store(v, (bf16x8*)(Sb + (size_t)(p0 + row) * Qpad + q0 + cc8));
  }

  for (int j = 0; j < 4; j++) {
    float v = cm[j];
    v = fmaxf(v, __shfl_xor(v, 16, 64));
    v = fmaxf(v, __shfl_xor(v, 32, 64));
    if (lq == 0 && v > -INFINITY) {
      int qc = q0 + wcol + j * 16 + lm;
      atomicMax(&dk[(size_t)n * Qpad + qc], fkey(v));
    }
  }
}

// ---- z partials: block = q-tile(2048) x p-slab(32/16); NO atomics;
// 16 row-loads in flight. exact 1D grid: 980 blocks ----
__global__ __launch_bounds__(256) void z_kernel(
    const __bf16* __restrict__ S3, const unsigned* __restrict__ dk3, float* __restrict__ Zp3,
    const __bf16* __restrict__ S4, const unsigned* __restrict__ dk4, float* __restrict__ Zp4)
{
  int id = blockIdx.x;
  const __bf16* S; const unsigned* dk; float* Zp;
  int Ppad, Qreal, Qpad, NSL, SLAB, n, qx, sy;
  if (id < 784) {
    n = id / 196; int r = id - n * 196; sy = r >> 1; qx = r & 1;
    S = S3; dk = dk3; Zp = Zp3; Ppad = 3200; Qreal = 3136; Qpad = 3200; NSL = 98; SLAB = 32;
  } else {
    id -= 784;
    n = id / 49; sy = id - n * 49; qx = 0;
    S = S4; dk = dk4; Zp = Zp4; Ppad = 896;  Qreal = 784;  Qpad = 896;  NSL = 49; SLAB = 16;
  }
  int q = (qx * 256 + threadIdx.x) * 8;
  if (q >= Qreal) return;
  float idv[8], nid[8];
  const unsigned* dkp = dk + (size_t)n * Qpad + q;
#pragma unroll
  for (int j = 0; j < 8; j++) {
    float mx = funkey(dkp[j]);
    float d = 0.5f * (1.f - mx) + EPSV;
    idv[j] = 1.f / d;
    nid[j] = -idv[j];
  }
  int p0 = sy * SLAB;
  const __bf16* Sp = S + (size_t)n * Ppad * Qpad + q;
  float acc[8] = {0.f, 0.f, 0.f, 0.f, 0.f, 0.f, 0.f, 0.f};
  for (int pb = 0; pb < SLAB; pb += 16) {
    bf16x8 sv[16];
#pragma unroll
    for (int r = 0; r < 16; r++)
      sv[r] = *(const bf16x8*)(Sp + (size_t)(p0 + pb + r) * Qpad);
#pragma unroll
    for (int r = 0; r < 16; r++)
      for (int j = 0; j < 8; j++)
        acc[j] += __expf(fmaf((float)sv[r][j], idv[j], nid[j]));
  }
  float* zp = Zp + ((size_t)n * NSL + sy) * Qpad + q;
  *(f32x4*)zp = f32x4{acc[0], acc[1], acc[2], acc[3]};
  *(f32x4*)(zp + 4) = f32x4{acc[4], acc[5], acc[6], acc[7]};
}

// ---- reduce: Z[q] = sum_slab Zp ; invd[q] ; c[q] = -log(Z)-invd ---- grid (13,8)
__global__ __launch_bounds__(256) void reduce_kernel(
    const float* __restrict__ Zp3, const unsigned* __restrict__ dk3,
    float* __restrict__ invd3, float* __restrict__ c3,
    const float* __restrict__ Zp4, const unsigned* __restrict__ dk4,
    float* __restrict__ invd4, float* __restrict__ c4)
{
  int lay = blockIdx.y >> 2, n = blockIdx.y & 3;
  const float* Zp; const unsigned* dk; float *invd, *c; int Qreal, Qpad, NSL;
  if (lay == 0) { Zp = Zp3; dk = dk3; invd = invd3; c = c3; Qreal = 3136; Qpad = 3200; NSL = 98; }
  else          { Zp = Zp4; dk = dk4; invd = invd4; c = c4; Qreal = 784;  Qpad = 896;  NSL = 49; }
  int q = blockIdx.x * 256 + threadIdx.x;
  if (q >= Qreal) return;
  float s0 = 0.f, s1 = 0.f, s2 = 0.f, s3 = 0.f;
  int sl = 0;
  for (; sl + 4 <= NSL; sl += 4) {
    s0 += Zp[((size_t)n * NSL + sl) * Qpad + q];
    s1 += Zp[((size_t)n * NSL + sl + 1) * Qpad + q];
    s2 += Zp[((size_t)n * NSL + sl + 2) * Qpad + q];
    s3 += Zp[((size_t)n * NSL + sl + 3) * Qpad + q];
  }
  for (; sl < NSL; sl++) s0 += Zp[((size_t)n * NSL + sl) * Qpad + q];
  float s = (s0 + s1) + (s2 + s3);
  float mx = funkey(dk[(size_t)n * Qpad + q]);
  float d = 0.5f * (1.f - mx) + EPSV;
  float idv = 1.f / d;
  invd[(size_t)n * Qpad + q] = idv;
  c[(size_t)n * Qpad + q] = -logf(s) - idv;
}

// ---- rowmax: kmax[p] = exp(max_q (S*invd + c)) ; 8 rows/block;
// exact 1D grid: 1960 blocks ----
__global__ __launch_bounds__(256) void rowmax_kernel(
    const __bf16* __restrict__ S3, const float* __restrict__ invd3,
    const float* __restrict__ c3, float* __restrict__ km3,
    const __bf16* __restrict__ S4, const float* __restrict__ invd4,
    const float* __restrict__ c4, float* __restrict__ km4)
{
  int id = blockIdx.x;
  const __bf16* S; const float *invd, *cc; float* kmax;
  int Qreal, Qpad, Ppad, n, blk;
  if (id < 1568) {
    n = id / 392; blk = id - n * 392;
    S = S3; invd = invd3; cc = c3; kmax = km3; Qreal = 3136; Qpad = 3200; Ppad = 3200;
  } else {
    id -= 1568;
    n = id / 98; blk = id - n * 98;
    S = S4; invd = invd4; cc = c4; kmax = km4; Qreal = 784;  Qpad = 896;  Ppad = 896;
  }
  int p0 = blk * 8;
  const __bf16* Sp = S + ((size_t)n * Ppad + p0) * Qpad;
  const float* idp = invd + (size_t)n * Qpad;
  const float* cp = cc + (size_t)n * Qpad;
  int nq8 = Qreal >> 3;
  float m[8];
#pragma unroll
  for (int r = 0; r < 8; r++) m[r] = -INFINITY;
  for (int i = threadIdx.x; i < nq8; i += 256) {
    f32x4 i0 = *(const f32x4*)(idp + (size_t)i * 8);
    f32x4 i1 = *(const f32x4*)(idp + (size_t)i * 8 + 4);
    f32x4 c0 = *(const f32x4*)(cp + (size_t)i * 8);
    f32x4 c1 = *(const f32x4*)(cp + (size_t)i * 8 + 4);
#pragma unroll
    for (int r = 0; r < 8; r++) {
      bf16x8 sv = *(const bf16x8*)(Sp + (size_t)r * Qpad + (size_t)i * 8);
      for (int j = 0; j < 4; j++)
        m[r] = fmaxf(m[r], fmaf((float)sv[j], i0[j], c0[j]));
      for (int j = 0; j < 4; j++)
        m[r] = fmaxf(m[r], fmaf((float)sv[j + 4], i1[j], c1[j]));
    }
  }
#pragma unroll
  for (int r = 0; r < 8; r++)
    for (int off = 32; off > 0; off >>= 1)
      m[r] = fmaxf(m[r], __shfl_xor(m[r], off, 64));
  __shared__ float red[4][8];
  int w = threadIdx.x >> 6;
  if ((threadIdx.x & 63) == 0)
    for (int r = 0; r < 8; r++) red[w][r] = m[r];
  __syncthreads();
  if (threadIdx.x < 8) {
    int r = threadIdx.x;
    float mr = fmaxf(fmaxf(red[0][r], red[1][r]), fmaxf(red[2][r], red[3][r]));
    kmax[(size_t)n * Ppad + p0 + r] = __expf(mr);
  }
}

// loss = 0.5 * sum_n -log(mean_p kmax3) + 1.0 * sum_n -log(mean_p kmax4)
__global__ void final_kernel(const float* __restrict__ kmax3, const float* __restrict__ kmax4,
                             float* __restrict__ out)
{
  __shared__ float red[256];
  int tid = threadIdx.x;
  float total = 0.f;
  for (int l = 0; l < 2; l++) {
    const float* km = l ? kmax4 : kmax3;
    int P = l ? 784 : 3136;
    int Ppad = l ? 896 : 3200;
    float wgt = l ? 1.0f : 0.5f;
    for (int n = 0; n < 4; n++) {
      float s = 0.f;
      for (int i = tid; i < P; i += 256) s += km[(size_t)n * Ppad + i];
      red[tid] = s;
      __syncthreads();
      for (int st = 128; st > 0; st >>= 1) {
        if (tid < st) red[tid] += red[tid + st];
        __syncthreads();
      }
      if (tid == 0) total += wgt * (-logf(red[0] / (float)P));
      __syncthreads();
    }
  }
  if (tid == 0) out[0] = total;
}

extern "C" void kernel_launch(void* const* d_in, const int* in_sizes, int n_in,
                              void* d_out, int out_size, void* d_ws, size_t ws_size,
                              hipStream_t stream)
{
  const float* gen3 = (const float*)d_in[0];
  const float* tar3 = (const float*)d_in[1];
  const float* gen4 = (const float*)d_in[2];
  const float* tar4 = (const float*)d_in[3];

  char* ws = (char*)d_ws;
  size_t off = 0;
  auto take = [&](size_t bytes) { char* p = ws + off; off += bytes; return p; };

  // ---- zeroed region (one contiguous memset) ----
  unsigned* divkey3 = (unsigned*)take(51200);   // 4*3200*4
  unsigned* divkey4 = (unsigned*)take(14336);   // 4*896*4
  size_t zero_bytes = off;
  // ---- rest ----
  __bf16* That3 = (__bf16*)take(6553600);       // 4*3200*256*2
  __bf16* Ghat3 = (__bf16*)take(6553600);
  __bf16* That4 = (__bf16*)take(3670016);       // 4*896*512*2
  __bf16* Ghat4 = (__bf16*)take(3670016);
  __bf16* S3    = (__bf16*)take(81920000);      // 4*3200*3200*2
  __bf16* S4    = (__bf16*)take(6422528);       // 4*896*896*2
  float*  Zp3   = (float*) take(5017600);       // 4*98*3200*4
  float*  Zp4   = (float*) take(702464);        // 4*49*896*4
  float* invd3  = (float*)take(51200);
  float* c3     = (float*)take(51200);
  float* kmax3  = (float*)take(51200);
  float* invd4  = (float*)take(14336);
  float* c4     = (float*)take(14336);
  float* kmax4  = (float*)take(14336);

  hipMemsetAsync(divkey3, 0, zero_bytes, stream);

  norm_kernel<<<dim3(1, 100, 8), 256, 0, stream>>>(gen3, tar3, Ghat3, That3,
                                                   gen4, tar4, Ghat4, That4);
  gemm_kernel<<<2696, 256, 0, stream>>>(That3, Ghat3, S3, divkey3,
                                        That4, Ghat4, S4, divkey4);
  z_kernel<<<980, 256, 0, stream>>>(S3, divkey3, Zp3,
                                    S4, divkey4, Zp4);
  reduce_kernel<<<dim3(13, 8), 256, 0, stream>>>(Zp3, divkey3, invd3, c3,
                                                 Zp4, divkey4, invd4, c4);
  rowmax_kernel<<<1960, 256, 0, stream>>>(S3, invd3, c3, kmax3,
                                          S4, invd4, c4, kmax4);
  final_kernel<<<1, 256, 0, stream>>>(kmax3, kmax4, (float*)d_out);
}

// Round 10
// 209.557 us; speedup vs baseline: 1.2356x; 1.2356x over previous
//
#include <hip/hip_runtime.h>
#include <math.h>

typedef __bf16 bf16x8 __attribute__((ext_vector_type(8)));
typedef float f32x4 __attribute__((ext_vector_type(4)));

#define EPSV 1e-5f
#define GLB(p) ((__attribute__((address_space(1))) void*)(p))
#define LDS(p) ((__attribute__((address_space(3))) void*)(p))

// ---- single-pass norm: block owns p-tile x all C; stats in regs+LDS, then
// apply+store bf16 [N][Ppad][C]. Pad blocks (y>=NWORK) zero the pad rows. ----
// grid (1, 100, 8): z>>2 = layer, z&3 = n.
__global__ __launch_bounds__(256) void norm_kernel(
    const float* __restrict__ g3, const float* __restrict__ t3,
    __bf16* __restrict__ G3, __bf16* __restrict__ T3,
    const float* __restrict__ g4, const float* __restrict__ t4,
    __bf16* __restrict__ G4, __bf16* __restrict__ T4)
{
  int lay = blockIdx.z >> 2, n = blockIdx.z & 3;
  const float *gen, *tar; __bf16 *Gh, *Th; int C, P, Ppad, PT, NWORK, NTOT, NG;
  if (lay == 0) { gen = g3; tar = t3; Gh = G3; Th = T3; C = 256; P = 3136; Ppad = 3200; PT = 32; NWORK = 98; NTOT = 100; NG = 8; }
  else          { gen = g4; tar = t4; Gh = G4; Th = T4; C = 512; P = 784;  Ppad = 896;  PT = 16; NWORK = 49; NTOT = 56;  NG = 16; }
  if (blockIdx.y >= (unsigned)NTOT) return;
  int pl, cg;
  if (lay == 0) { pl = threadIdx.x & 31; cg = threadIdx.x >> 5; }
  else          { pl = threadIdx.x & 15; cg = threadIdx.x >> 4; }
  int c0 = cg * 32;

  if (blockIdx.y >= (unsigned)NWORK) {  // zero pad rows
    int p = P + (blockIdx.y - NWORK) * PT + pl;
    if (p < Ppad) {
      __bf16* tp = Th + ((size_t)n * Ppad + p) * C + c0;
      __bf16* gp = Gh + ((size_t)n * Ppad + p) * C + c0;
      bf16x8 z;
      for (int j = 0; j < 8; j++) z[j] = (__bf16)0.f;
      for (int j = 0; j < 32; j += 8) { *(bf16x8*)(tp + j) = z; *(bf16x8*)(gp + j) = z; }
    }
    return;
  }

  int p = blockIdx.y * PT + pl;
  const float* tb = tar + (size_t)n * C * P + (size_t)c0 * P + p;
  const float* gb = gen + (size_t)n * C * P + (size_t)c0 * P + p;
  float tv[32], gv[32];
  float st = 0.f, sst = 0.f, sg = 0.f, ssg = 0.f;
#pragma unroll
  for (int j = 0; j < 32; j++) {
    tv[j] = tb[(size_t)j * P];
    gv[j] = gb[(size_t)j * P];
  }
#pragma unroll
  for (int j = 0; j < 32; j++) {
    st += tv[j]; sst += tv[j] * tv[j];
    sg += gv[j]; ssg += gv[j] * gv[j];
  }
  __shared__ f32x4 red[16][32];
  red[cg][pl] = f32x4{st, sst, sg, ssg};
  __syncthreads();
  for (int h = NG >> 1; h > 0; h >>= 1) {
    if (cg < h) {
      f32x4 a = red[cg][pl], b = red[cg + h][pl];
      red[cg][pl] = f32x4{a[0] + b[0], a[1] + b[1], a[2] + b[2], a[3] + b[3]};
    }
    __syncthreads();
  }
  f32x4 s = red[0][pl];
  float m = s[0] / (float)C;
  float vt = s[1] - s[0] * s[0] / (float)C;
  float vg = s[3] - 2.f * m * s[2] + (float)C * m * m;
  float it = rsqrtf(fmaxf(vt, 1e-30f));
  float ig = rsqrtf(fmaxf(vg, 1e-30f));
  __bf16* tp = Th + ((size_t)n * Ppad + p) * C + c0;
  __bf16* gp = Gh + ((size_t)n * Ppad + p) * C + c0;
#pragma unroll
  for (int j0 = 0; j0 < 32; j0 += 8) {
    bf16x8 to, go;
    for (int j = 0; j < 8; j++) {
      to[j] = (__bf16)((tv[j0 + j] - m) * it);
      go[j] = (__bf16)((gv[j0 + j] - m) * ig);
    }
    *(bf16x8*)(tp + j0) = to;
    *(bf16x8*)(gp + j0) = go;
  }
}

// ---- GEMM: 128x128 tile, BK=64 per barrier-phase (two proven-swizzle BK=32
// LDS buffers -> 8 load_lds in flight, one barrier pair / 64 K), lb(256,4),
// conflict-free 296-B epilogue bounce, non-temporal S stores, colmax partial
// stores (NO atomics): Cm[n][pt*2+rowhalf][q]. ----
__global__ __launch_bounds__(256, 4) void gemm_kernel(
    const __bf16* __restrict__ A3, const __bf16* __restrict__ B3,
    __bf16* __restrict__ So3, float* __restrict__ Cm3,
    const __bf16* __restrict__ A4, const __bf16* __restrict__ B4,
    __bf16* __restrict__ So4, float* __restrict__ Cm4)
{
  // staging: A0 [0,8K) A1 [8K,16K) B0 [16K,24K) B1 [24K,32K)
  // epilogue reuse: 128 rows x 296 B = 37888 B
  __shared__ __attribute__((aligned(16))) char smem[37888];

  int id = blockIdx.x;
  const __bf16 *A, *B; __bf16* S; float* Cm;
  int C, Ppad, Qpad, Preal, NT, n, t;
  if (id < 2500) {
    n = id / 625; t = id - n * 625;
    A = A3; B = B3; S = So3; Cm = Cm3; C = 256; Ppad = 3200; Qpad = 3200; Preal = 3136; NT = 25;
  } else {
    id -= 2500;
    n = id / 49; t = id - n * 49;
    A = A4; B = B4; S = So4; Cm = Cm4; C = 512; Ppad = 896;  Qpad = 896;  Preal = 784;  NT = 7;
  }
  // band swizzle: bands of 8 p-tiles, q fastest within a band
  int bpb = NT * 8;
  int b = t / bpb, r = t - b * bpb;
  int rem = NT - b * 8;
  int h = rem < 8 ? rem : 8;
  int pt = b * 8 + r % h, qt = r / h;
  int p0 = pt * 128, q0 = qt * 128;

  int tid = threadIdx.x;
  int w = tid >> 6, lane = tid & 63;
  int lm = lane & 15, lq = lane >> 4;
  int wrow = (w >> 1) * 64, wcol = (w & 1) * 64;

  // staging: thread tid -> row tid>>2 (and +64), chunk-slot tid&3 (16B);
  // slot s of row r holds global chunk s ^ ((r>>1)&3) (proven 0-conflict).
  int srow = tid >> 2;
  int scol = ((tid & 3) ^ ((tid >> 3) & 3)) * 8;
  const __bf16* gA = A + ((size_t)n * Ppad + p0 + srow) * C + scol;
  const __bf16* gB = B + ((size_t)n * Qpad + q0 + srow) * C + scol;
  size_t rowoff = (size_t)64 * C;

  // fragment read: row R + chunk lq -> slot lq ^ ((lm>>1)&3)
  int sl = lq ^ ((lm >> 1) & 3);
  int aoff = (wrow + lm) * 64 + sl * 16;   // + i*1024 per i-tile
  int boff = (wcol + lm) * 64 + sl * 16;

  f32x4 acc[4][4];
  for (int i = 0; i < 4; i++)
    for (int j = 0; j < 4; j++)
      acc[i][j] = f32x4{0.f, 0.f, 0.f, 0.f};

  for (int k0 = 0; k0 < C; k0 += 64) {
    __syncthreads();
#pragma unroll
    for (int sub = 0; sub < 2; sub++) {
      int kk = k0 + sub * 32;
      char* a = smem + sub * 8192 + w * 1024;
      char* bb = smem + 16384 + sub * 8192 + w * 1024;
      __builtin_amdgcn_global_load_lds(GLB(gA + kk), LDS(a), 16, 0, 0);
      __builtin_amdgcn_global_load_lds(GLB(gA + rowoff + kk), LDS(a + 4096), 16, 0, 0);
      __builtin_amdgcn_global_load_lds(GLB(gB + kk), LDS(bb), 16, 0, 0);
      __builtin_amdgcn_global_load_lds(GLB(gB + rowoff + kk), LDS(bb + 4096), 16, 0, 0);
    }
    __syncthreads();
#pragma unroll
    for (int sub = 0; sub < 2; sub++) {
      const char* ab = smem + sub * 8192;
      const char* bb = smem + 16384 + sub * 8192;
      bf16x8 af[4], bf[4];
      for (int i = 0; i < 4; i++) af[i] = *(const bf16x8*)(ab + aoff + i * 1024);
      for (int j = 0; j < 4; j++) bf[j] = *(const bf16x8*)(bb + boff + j * 1024);
      for (int i = 0; i < 4; i++)
        for (int j = 0; j < 4; j++)
          acc[i][j] = __builtin_amdgcn_mfma_f32_16x16x32_bf16(af[i], bf[j], acc[i][j], 0, 0, 0);
    }
  }

  // colmax from registers (D: row = lq*4+ri, col = lm within 16x16 sub-tile)
  float cm[4] = {-INFINITY, -INFINITY, -INFINITY, -INFINITY};
  for (int i = 0; i < 4; i++)
    for (int j = 0; j < 4; j++)
      for (int ri = 0; ri < 4; ri++) {
        int pr = p0 + wrow + i * 16 + lq * 4 + ri;
        if (pr < Preal) cm[j] = fmaxf(cm[j], (float)(__bf16)acc[i][j][ri]);
      }

  // epilogue: bounce through LDS (296-B pitch, conflict-free), then
  // fully-coalesced non-temporal bf16x8 row stores.
  __syncthreads();
  for (int i = 0; i < 4; i++) {
    for (int j = 0; j < 4; j++) {
      int row = wrow + i * 16 + lq * 4;
      int col = wcol + j * 16 + lm;
      for (int ri = 0; ri < 4; ri++)
        *(__bf16*)(smem + (row + ri) * 296 + col * 2) = (__bf16)acc[i][j][ri];
    }
  }
  __syncthreads();
  __bf16* Sb = S + (size_t)n * Ppad * Qpad;
  int rr = tid >> 4, cc8 = (tid & 15) * 8;
  for (int r8 = 0; r8 < 8; r8++) {
    int row = r8 * 16 + rr;
    bf16x8 v = *(const bf16x8*)(smem + row * 296 + cc8 * 2);
    __builtin_nontemporal_store(v, (bf16x8*)(Sb + (size_t)(p0 + row) * Qpad + q0 + cc8));
  }

  // colmax partials: wave (wrow-half) reduces its 2 lq-halves, lanes lq==0
  // store 64 columns at Cm[n][pt*2 + rowhalf][qcol]  (plain stores, no atomics)
  for (int j = 0; j < 4; j++) {
    float v = cm[j];
    v = fmaxf(v, __shfl_xor(v, 16, 64));
    v = fmaxf(v, __shfl_xor(v, 32, 64));
    if (lq == 0) {
      int qc = q0 + wcol + j * 16 + lm;
      Cm[((size_t)n * NT * 2 + pt * 2 + (w >> 1)) * Qpad + qc] = v;
    }
  }
}

// ---- invd: reduce Cm partials -> invd[q] = 1/(0.5*(1-colmax)+eps) ----
// grid (13, 8): y>>2 = layer, y&3 = n.
__global__ __launch_bounds__(256) void invd_kernel(
    const float* __restrict__ Cm3, float* __restrict__ invd3,
    const float* __restrict__ Cm4, float* __restrict__ invd4)
{
  int lay = blockIdx.y >> 2, n = blockIdx.y & 3;
  const float* Cm; float* invd; int Qreal, Qpad, NP;
  if (lay == 0) { Cm = Cm3; invd = invd3; Qreal = 3136; Qpad = 3200; NP = 50; }
  else          { Cm = Cm4; invd = invd4; Qreal = 784;  Qpad = 896;  NP = 14; }
  int q = blockIdx.x * 256 + threadIdx.x;
  if (q >= Qreal) return;
  float mx = -INFINITY;
  for (int i = 0; i < NP; i++)
    mx = fmaxf(mx, Cm[((size_t)n * NP + i) * Qpad + q]);
  float d = 0.5f * (1.f - mx) + EPSV;
  invd[(size_t)n * Qpad + q] = 1.f / d;
}

// ---- z partials: block = q-tile(2048) x p-slab(32/16); NO atomics;
// 8 row-loads in flight. exact 1D grid: 980 blocks ----
__global__ __launch_bounds__(256) void z_kernel(
    const __bf16* __restrict__ S3, const float* __restrict__ invd3, float* __restrict__ Zp3,
    const __bf16* __restrict__ S4, const float* __restrict__ invd4, float* __restrict__ Zp4)
{
  int id = blockIdx.x;
  const __bf16* S; const float* invd; float* Zp;
  int Ppad, Qreal, Qpad, NSL, SLAB, n, qx, sy;
  if (id < 784) {
    n = id / 196; int r = id - n * 196; sy = r >> 1; qx = r & 1;
    S = S3; invd = invd3; Zp = Zp3; Ppad = 3200; Qreal = 3136; Qpad = 3200; NSL = 98; SLAB = 32;
  } else {
    id -= 784;
    n = id / 49; sy = id - n * 49; qx = 0;
    S = S4; invd = invd4; Zp = Zp4; Ppad = 896;  Qreal = 784;  Qpad = 896;  NSL = 49; SLAB = 16;
  }
  int q = (qx * 256 + threadIdx.x) * 8;
  if (q >= Qreal) return;
  float idv[8], nid[8];
  const float* ip = invd + (size_t)n * Qpad + q;
#pragma unroll
  for (int j = 0; j < 8; j++) {
    idv[j] = ip[j];
    nid[j] = -idv[j];
  }
  int p0 = sy * SLAB;
  const __bf16* Sp = S + (size_t)n * Ppad * Qpad + q;
  float acc[8] = {0.f, 0.f, 0.f, 0.f, 0.f, 0.f, 0.f, 0.f};
  for (int pb = 0; pb < SLAB; pb += 8) {
    bf16x8 sv[8];
#pragma unroll
    for (int r = 0; r < 8; r++)
      sv[r] = *(const bf16x8*)(Sp + (size_t)(p0 + pb + r) * Qpad);
#pragma unroll
    for (int r = 0; r < 8; r++)
      for (int j = 0; j < 8; j++)
        acc[j] += __expf(fmaf((float)sv[r][j], idv[j], nid[j]));
  }
  float* zp = Zp + ((size_t)n * NSL + sy) * Qpad + q;
  *(f32x4*)zp = f32x4{acc[0], acc[1], acc[2], acc[3]};
  *(f32x4*)(zp + 4) = f32x4{acc[4], acc[5], acc[6], acc[7]};
}

// ---- reduce: Z[q] = sum_slab Zp ; c[q] = -log(Z)-invd ---- grid (13,8)
__global__ __launch_bounds__(256) void reduce_kernel(
    const float* __restrict__ Zp3, const float* __restrict__ invd3, float* __restrict__ c3,
    const float* __restrict__ Zp4, const float* __restrict__ invd4, float* __restrict__ c4)
{
  int lay = blockIdx.y >> 2, n = blockIdx.y & 3;
  const float *Zp, *invd; float* c; int Qreal, Qpad, NSL;
  if (lay == 0) { Zp = Zp3; invd = invd3; c = c3; Qreal = 3136; Qpad = 3200; NSL = 98; }
  else          { Zp = Zp4; invd = invd4; c = c4; Qreal = 784;  Qpad = 896;  NSL = 49; }
  int q = blockIdx.x * 256 + threadIdx.x;
  if (q >= Qreal) return;
  float s0 = 0.f, s1 = 0.f, s2 = 0.f, s3 = 0.f;
  int sl = 0;
  for (; sl + 4 <= NSL; sl += 4) {
    s0 += Zp[((size_t)n * NSL + sl) * Qpad + q];
    s1 += Zp[((size_t)n * NSL + sl + 1) * Qpad + q];
    s2 += Zp[((size_t)n * NSL + sl + 2) * Qpad + q];
    s3 += Zp[((size_t)n * NSL + sl + 3) * Qpad + q];
  }
  for (; sl < NSL; sl++) s0 += Zp[((size_t)n * NSL + sl) * Qpad + q];
  float s = (s0 + s1) + (s2 + s3);
  c[(size_t)n * Qpad + q] = -logf(s) - invd[(size_t)n * Qpad + q];
}

// ---- rowmax: kmax[p] = exp(max_q (S*invd + c)) ; 8 rows/block;
// exact 1D grid: 1960 blocks ----
__global__ __launch_bounds__(256) void rowmax_kernel(
    const __bf16* __restrict__ S3, const float* __restrict__ invd3,
    const float* __restrict__ c3, float* __restrict__ km3,
    const __bf16* __restrict__ S4, const float* __restrict__ invd4,
    const float* __restrict__ c4, float* __restrict__ km4)
{
  int id = blockIdx.x;
  const __bf16* S; const float *invd, *cc; float* kmax;
  int Qreal, Qpad, Ppad, n, blk;
  if (id < 1568) {
    n = id / 392; blk = id - n * 392;
    S = S3; invd = invd3; cc = c3; kmax = km3; Qreal = 3136; Qpad = 3200; Ppad = 3200;
  } else {
    id -= 1568;
    n = id / 98; blk = id - n * 98;
    S = S4; invd = invd4; cc = c4; kmax = km4; Qreal = 784;  Qpad = 896;  Ppad = 896;
  }
  int p0 = blk * 8;
  const __bf16* Sp = S + ((size_t)n * Ppad + p0) * Qpad;
  const float* idp = invd + (size_t)n * Qpad;
  const float* cp = cc + (size_t)n * Qpad;
  int nq8 = Qreal >> 3;
  float m[8];
#pragma unroll
  for (int r = 0; r < 8; r++) m[r] = -INFINITY;
  for (int i = threadIdx.x; i < nq8; i += 256) {
    f32x4 i0 = *(const f32x4*)(idp + (size_t)i * 8);
    f32x4 i1 = *(const f32x4*)(idp + (size_t)i * 8 + 4);
    f32x4 c0 = *(const f32x4*)(cp + (size_t)i * 8);
    f32x4 c1 = *(const f32x4*)(cp + (size_t)i * 8 + 4);
#pragma unroll
    for (int r = 0; r < 8; r++) {
      bf16x8 sv = *(const bf16x8*)(Sp + (size_t)r * Qpad + (size_t)i * 8);
      for (int j = 0; j < 4; j++)
        m[r] = fmaxf(m[r], fmaf((float)sv[j], i0[j], c0[j]));
      for (int j = 0; j < 4; j++)
        m[r] = fmaxf(m[r], fmaf((float)sv[j + 4], i1[j], c1[j]));
    }
  }
#pragma unroll
  for (int r = 0; r < 8; r++)
    for (int off = 32; off > 0; off >>= 1)
      m[r] = fmaxf(m[r], __shfl_xor(m[r], off, 64));
  __shared__ float red[4][8];
  int w = threadIdx.x >> 6;
  if ((threadIdx.x & 63) == 0)
    for (int r = 0; r < 8; r++) red[w][r] = m[r];
  __syncthreads();
  if (threadIdx.x < 8) {
    int r = threadIdx.x;
    float mr = fmaxf(fmaxf(red[0][r], red[1][r]), fmaxf(red[2][r], red[3][r]));
    kmax[(size_t)n * Ppad + p0 + r] = __expf(mr);
  }
}

// loss = 0.5 * sum_n -log(mean_p kmax3) + 1.0 * sum_n -log(mean_p kmax4)
__global__ void final_kernel(const float* __restrict__ kmax3, const float* __restrict__ kmax4,
                             float* __restrict__ out)
{
  __shared__ float red[256];
  int tid = threadIdx.x;
  float total = 0.f;
  for (int l = 0; l < 2; l++) {
    const float* km = l ? kmax4 : kmax3;
    int P = l ? 784 : 3136;
    int Ppad = l ? 896 : 3200;
    float wgt = l ? 1.0f : 0.5f;
    for (int n = 0; n < 4; n++) {
      float s = 0.f;
      for (int i = tid; i < P; i += 256) s += km[(size_t)n * Ppad + i];
      red[tid] = s;
      __syncthreads();
      for (int st = 128; st > 0; st >>= 1) {
        if (tid < st) red[tid] += red[tid + st];
        __syncthreads();
      }
      if (tid == 0) total += wgt * (-logf(red[0] / (float)P));
      __syncthreads();
    }
  }
  if (tid == 0) out[0] = total;
}

extern "C" void kernel_launch(void* const* d_in, const int* in_sizes, int n_in,
                              void* d_out, int out_size, void* d_ws, size_t ws_size,
                              hipStream_t stream)
{
  const float* gen3 = (const float*)d_in[0];
  const float* tar3 = (const float*)d_in[1];
  const float* gen4 = (const float*)d_in[2];
  const float* tar4 = (const float*)d_in[3];

  char* ws = (char*)d_ws;
  size_t off = 0;
  auto take = [&](size_t bytes) { char* p = ws + off; off += bytes; return p; };

  __bf16* That3 = (__bf16*)take(6553600);       // 4*3200*256*2
  __bf16* Ghat3 = (__bf16*)take(6553600);
  __bf16* That4 = (__bf16*)take(3670016);       // 4*896*512*2
  __bf16* Ghat4 = (__bf16*)take(3670016);
  __bf16* S3    = (__bf16*)take(81920000);      // 4*3200*3200*2
  __bf16* S4    = (__bf16*)take(6422528);       // 4*896*896*2
  float*  Cm3   = (float*) take(2560000);       // 4*50*3200*4
  float*  Cm4   = (float*) take(200704);        // 4*14*896*4
  float*  Zp3   = (float*) take(5017600);       // 4*98*3200*4
  float*  Zp4   = (float*) take(702464);        // 4*49*896*4
  float* invd3  = (float*)take(51200);
  float* c3     = (float*)take(51200);
  float* kmax3  = (float*)take(51200);
  float* invd4  = (float*)take(14336);
  float* c4     = (float*)take(14336);
  float* kmax4  = (float*)take(14336);

  norm_kernel<<<dim3(1, 100, 8), 256, 0, stream>>>(gen3, tar3, Ghat3, That3,
                                                   gen4, tar4, Ghat4, That4);
  gemm_kernel<<<2696, 256, 0, stream>>>(That3, Ghat3, S3, Cm3,
                                        That4, Ghat4, S4, Cm4);
  invd_kernel<<<dim3(13, 8), 256, 0, stream>>>(Cm3, invd3, Cm4, invd4);
  z_kernel<<<980, 256, 0, stream>>>(S3, invd3, Zp3,
                                    S4, invd4, Zp4);
  reduce_kernel<<<dim3(13, 8), 256, 0, stream>>>(Zp3, invd3, c3,
                                                 Zp4, invd4, c4);
  rowmax_kernel<<<1960, 256, 0, stream>>>(S3, invd3, c3, kmax3,
                                          S4, invd4, c4, kmax4);
  final_kernel<<<1, 256, 0, stream>>>(kmax3, kmax4, (float*)d_out);
}

// Round 11
// 209.344 us; speedup vs baseline: 1.2368x; 1.0010x over previous
//
#include <hip/hip_runtime.h>
#include <math.h>

typedef __bf16 bf16x8 __attribute__((ext_vector_type(8)));
typedef float f32x4 __attribute__((ext_vector_type(4)));

#define EPSV 1e-5f
#define GLB(p) ((__attribute__((address_space(1))) void*)(p))
#define LDS(p) ((__attribute__((address_space(3))) void*)(p))

// ---- single-pass norm: block owns p-tile x all C; stats in regs+LDS, then
// apply+store bf16 [N][Ppad][C]. Pad blocks (y>=NWORK) zero the pad rows. ----
// grid (1, 100, 8): z>>2 = layer, z&3 = n.
__global__ __launch_bounds__(256) void norm_kernel(
    const float* __restrict__ g3, const float* __restrict__ t3,
    __bf16* __restrict__ G3, __bf16* __restrict__ T3,
    const float* __restrict__ g4, const float* __restrict__ t4,
    __bf16* __restrict__ G4, __bf16* __restrict__ T4)
{
  int lay = blockIdx.z >> 2, n = blockIdx.z & 3;
  const float *gen, *tar; __bf16 *Gh, *Th; int C, P, Ppad, PT, NWORK, NTOT, NG;
  if (lay == 0) { gen = g3; tar = t3; Gh = G3; Th = T3; C = 256; P = 3136; Ppad = 3200; PT = 32; NWORK = 98; NTOT = 100; NG = 8; }
  else          { gen = g4; tar = t4; Gh = G4; Th = T4; C = 512; P = 784;  Ppad = 896;  PT = 16; NWORK = 49; NTOT = 56;  NG = 16; }
  if (blockIdx.y >= (unsigned)NTOT) return;
  int pl, cg;
  if (lay == 0) { pl = threadIdx.x & 31; cg = threadIdx.x >> 5; }
  else          { pl = threadIdx.x & 15; cg = threadIdx.x >> 4; }
  int c0 = cg * 32;

  if (blockIdx.y >= (unsigned)NWORK) {  // zero pad rows
    int p = P + (blockIdx.y - NWORK) * PT + pl;
    if (p < Ppad) {
      __bf16* tp = Th + ((size_t)n * Ppad + p) * C + c0;
      __bf16* gp = Gh + ((size_t)n * Ppad + p) * C + c0;
      bf16x8 z;
      for (int j = 0; j < 8; j++) z[j] = (__bf16)0.f;
      for (int j = 0; j < 32; j += 8) { *(bf16x8*)(tp + j) = z; *(bf16x8*)(gp + j) = z; }
    }
    return;
  }

  int p = blockIdx.y * PT + pl;
  const float* tb = tar + (size_t)n * C * P + (size_t)c0 * P + p;
  const float* gb = gen + (size_t)n * C * P + (size_t)c0 * P + p;
  float tv[32], gv[32];
  float st = 0.f, sst = 0.f, sg = 0.f, ssg = 0.f;
#pragma unroll
  for (int j = 0; j < 32; j++) {
    tv[j] = tb[(size_t)j * P];
    gv[j] = gb[(size_t)j * P];
  }
#pragma unroll
  for (int j = 0; j < 32; j++) {
    st += tv[j]; sst += tv[j] * tv[j];
    sg += gv[j]; ssg += gv[j] * gv[j];
  }
  __shared__ f32x4 red[16][32];
  red[cg][pl] = f32x4{st, sst, sg, ssg};
  __syncthreads();
  for (int h = NG >> 1; h > 0; h >>= 1) {
    if (cg < h) {
      f32x4 a = red[cg][pl], b = red[cg + h][pl];
      red[cg][pl] = f32x4{a[0] + b[0], a[1] + b[1], a[2] + b[2], a[3] + b[3]};
    }
    __syncthreads();
  }
  f32x4 s = red[0][pl];
  float m = s[0] / (float)C;
  float vt = s[1] - s[0] * s[0] / (float)C;
  float vg = s[3] - 2.f * m * s[2] + (float)C * m * m;
  float it = rsqrtf(fmaxf(vt, 1e-30f));
  float ig = rsqrtf(fmaxf(vg, 1e-30f));
  __bf16* tp = Th + ((size_t)n * Ppad + p) * C + c0;
  __bf16* gp = Gh + ((size_t)n * Ppad + p) * C + c0;
#pragma unroll
  for (int j0 = 0; j0 < 32; j0 += 8) {
    bf16x8 to, go;
    for (int j = 0; j < 8; j++) {
      to[j] = (__bf16)((tv[j0 + j] - m) * it);
      go[j] = (__bf16)((gv[j0 + j] - m) * ig);
    }
    *(bf16x8*)(tp + j0) = to;
    *(bf16x8*)(gp + j0) = go;
  }
}

// ---- GEMM: 128x128 tile, BK=64 per barrier-phase (two proven-swizzle BK=32
// LDS buffers -> 8 load_lds in flight, one barrier pair / 64 K), lb(256,3),
// conflict-free 296-B epilogue bounce, CACHED S stores (S fits the 256-MB L3
// and z/rowmax re-read it -- nt stores bypassed L3 and starved them),
// colmax partial stores (NO atomics): Cm[n][pt*2+rowhalf][q]. ----
__global__ __launch_bounds__(256, 3) void gemm_kernel(
    const __bf16* __restrict__ A3, const __bf16* __restrict__ B3,
    __bf16* __restrict__ So3, float* __restrict__ Cm3,
    const __bf16* __restrict__ A4, const __bf16* __restrict__ B4,
    __bf16* __restrict__ So4, float* __restrict__ Cm4)
{
  // staging: A0 [0,8K) A1 [8K,16K) B0 [16K,24K) B1 [24K,32K)
  // epilogue reuse: 128 rows x 296 B = 37888 B
  __shared__ __attribute__((aligned(16))) char smem[37888];

  int id = blockIdx.x;
  const __bf16 *A, *B; __bf16* S; float* Cm;
  int C, Ppad, Qpad, Preal, NT, n, t;
  if (id < 2500) {
    n = id / 625; t = id - n * 625;
    A = A3; B = B3; S = So3; Cm = Cm3; C = 256; Ppad = 3200; Qpad = 3200; Preal = 3136; NT = 25;
  } else {
    id -= 2500;
    n = id / 49; t = id - n * 49;
    A = A4; B = B4; S = So4; Cm = Cm4; C = 512; Ppad = 896;  Qpad = 896;  Preal = 784;  NT = 7;
  }
  // band swizzle: bands of 8 p-tiles, q fastest within a band
  int bpb = NT * 8;
  int b = t / bpb, r = t - b * bpb;
  int rem = NT - b * 8;
  int h = rem < 8 ? rem : 8;
  int pt = b * 8 + r % h, qt = r / h;
  int p0 = pt * 128, q0 = qt * 128;

  int tid = threadIdx.x;
  int w = tid >> 6, lane = tid & 63;
  int lm = lane & 15, lq = lane >> 4;
  int wrow = (w >> 1) * 64, wcol = (w & 1) * 64;

  // staging: thread tid -> row tid>>2 (and +64), chunk-slot tid&3 (16B);
  // slot s of row r holds global chunk s ^ ((r>>1)&3) (proven 0-conflict).
  int srow = tid >> 2;
  int scol = ((tid & 3) ^ ((tid >> 3) & 3)) * 8;
  const __bf16* gA = A + ((size_t)n * Ppad + p0 + srow) * C + scol;
  const __bf16* gB = B + ((size_t)n * Qpad + q0 + srow) * C + scol;
  size_t rowoff = (size_t)64 * C;

  // fragment read: row R + chunk lq -> slot lq ^ ((lm>>1)&3)
  int sl = lq ^ ((lm >> 1) & 3);
  int aoff = (wrow + lm) * 64 + sl * 16;   // + i*1024 per i-tile
  int boff = (wcol + lm) * 64 + sl * 16;

  f32x4 acc[4][4];
  for (int i = 0; i < 4; i++)
    for (int j = 0; j < 4; j++)
      acc[i][j] = f32x4{0.f, 0.f, 0.f, 0.f};

  for (int k0 = 0; k0 < C; k0 += 64) {
    __syncthreads();
#pragma unroll
    for (int sub = 0; sub < 2; sub++) {
      int kk = k0 + sub * 32;
      char* a = smem + sub * 8192 + w * 1024;
      char* bb = smem + 16384 + sub * 8192 + w * 1024;
      __builtin_amdgcn_global_load_lds(GLB(gA + kk), LDS(a), 16, 0, 0);
      __builtin_amdgcn_global_load_lds(GLB(gA + rowoff + kk), LDS(a + 4096), 16, 0, 0);
      __builtin_amdgcn_global_load_lds(GLB(gB + kk), LDS(bb), 16, 0, 0);
      __builtin_amdgcn_global_load_lds(GLB(gB + rowoff + kk), LDS(bb + 4096), 16, 0, 0);
    }
    __syncthreads();
#pragma unroll
    for (int sub = 0; sub < 2; sub++) {
      const char* ab = smem + sub * 8192;
      const char* bb = smem + 16384 + sub * 8192;
      bf16x8 af[4], bf[4];
      for (int i = 0; i < 4; i++) af[i] = *(const bf16x8*)(ab + aoff + i * 1024);
      for (int j = 0; j < 4; j++) bf[j] = *(const bf16x8*)(bb + boff + j * 1024);
      for (int i = 0; i < 4; i++)
        for (int j = 0; j < 4; j++)
          acc[i][j] = __builtin_amdgcn_mfma_f32_16x16x32_bf16(af[i], bf[j], acc[i][j], 0, 0, 0);
    }
  }

  // colmax from registers (D: row = lq*4+ri, col = lm within 16x16 sub-tile)
  float cm[4] = {-INFINITY, -INFINITY, -INFINITY, -INFINITY};
  for (int i = 0; i < 4; i++)
    for (int j = 0; j < 4; j++)
      for (int ri = 0; ri < 4; ri++) {
        int pr = p0 + wrow + i * 16 + lq * 4 + ri;
        if (pr < Preal) cm[j] = fmaxf(cm[j], (float)(__bf16)acc[i][j][ri]);
      }

  // epilogue: bounce through LDS (296-B pitch, conflict-free), then
  // fully-coalesced CACHED bf16x8 row stores (S must land in L3).
  __syncthreads();
  for (int i = 0; i < 4; i++) {
    for (int j = 0; j < 4; j++) {
      int row = wrow + i * 16 + lq * 4;
      int col = wcol + j * 16 + lm;
      for (int ri = 0; ri < 4; ri++)
        *(__bf16*)(smem + (row + ri) * 296 + col * 2) = (__bf16)acc[i][j][ri];
    }
  }
  __syncthreads();
  __bf16* Sb = S + (size_t)n * Ppad * Qpad;
  int rr = tid >> 4, cc8 = (tid & 15) * 8;
  for (int r8 = 0; r8 < 8; r8++) {
    int row = r8 * 16 + rr;
    bf16x8 v = *(const bf16x8*)(smem + row * 296 + cc8 * 2);
    *(bf16x8*)(Sb + (size_t)(p0 + row) * Qpad + q0 + cc8) = v;
  }

  // colmax partials: lanes lq==0 store 64 columns at Cm[n][pt*2+rowhalf][qcol]
  for (int j = 0; j < 4; j++) {
    float v = cm[j];
    v = fmaxf(v, __shfl_xor(v, 16, 64));
    v = fmaxf(v, __shfl_xor(v, 32, 64));
    if (lq == 0) {
      int qc = q0 + wcol + j * 16 + lm;
      Cm[((size_t)n * NT * 2 + pt * 2 + (w >> 1)) * Qpad + qc] = v;
    }
  }
}

// ---- invd: reduce Cm partials -> invd[q] = 1/(0.5*(1-colmax)+eps) ----
// grid (13, 8): y>>2 = layer, y&3 = n.
__global__ __launch_bounds__(256) void invd_kernel(
    const float* __restrict__ Cm3, float* __restrict__ invd3,
    const float* __restrict__ Cm4, float* __restrict__ invd4)
{
  int lay = blockIdx.y >> 2, n = blockIdx.y & 3;
  const float* Cm; float* invd; int Qreal, Qpad, NP;
  if (lay == 0) { Cm = Cm3; invd = invd3; Qreal = 3136; Qpad = 3200; NP = 50; }
  else          { Cm = Cm4; invd = invd4; Qreal = 784;  Qpad = 896;  NP = 14; }
  int q = blockIdx.x * 256 + threadIdx.x;
  if (q >= Qreal) return;
  float mx = -INFINITY;
  for (int i = 0; i < NP; i++)
    mx = fmaxf(mx, Cm[((size_t)n * NP + i) * Qpad + q]);
  float d = 0.5f * (1.f - mx) + EPSV;
  invd[(size_t)n * Qpad + q] = 1.f / d;
}

// ---- z partials: block = q-tile(2048) x p-slab(32/16); NO atomics;
// 8 row-loads in flight. exact 1D grid: 980 blocks ----
__global__ __launch_bounds__(256) void z_kernel(
    const __bf16* __restrict__ S3, const float* __restrict__ invd3, float* __restrict__ Zp3,
    const __bf16* __restrict__ S4, const float* __restrict__ invd4, float* __restrict__ Zp4)
{
  int id = blockIdx.x;
  const __bf16* S; const float* invd; float* Zp;
  int Ppad, Qreal, Qpad, NSL, SLAB, n, qx, sy;
  if (id < 784) {
    n = id / 196; int r = id - n * 196; sy = r >> 1; qx = r & 1;
    S = S3; invd = invd3; Zp = Zp3; Ppad = 3200; Qreal = 3136; Qpad = 3200; NSL = 98; SLAB = 32;
  } else {
    id -= 784;
    n = id / 49; sy = id - n * 49; qx = 0;
    S = S4; invd = invd4; Zp = Zp4; Ppad = 896;  Qreal = 784;  Qpad = 896;  NSL = 49; SLAB = 16;
  }
  int q = (qx * 256 + threadIdx.x) * 8;
  if (q >= Qreal) return;
  float idv[8], nid[8];
  const float* ip = invd + (size_t)n * Qpad + q;
#pragma unroll
  for (int j = 0; j < 8; j++) {
    idv[j] = ip[j];
    nid[j] = -idv[j];
  }
  int p0 = sy * SLAB;
  const __bf16* Sp = S + (size_t)n * Ppad * Qpad + q;
  float acc[8] = {0.f, 0.f, 0.f, 0.f, 0.f, 0.f, 0.f, 0.f};
  for (int pb = 0; pb < SLAB; pb += 8) {
    bf16x8 sv[8];
#pragma unroll
    for (int r = 0; r < 8; r++)
      sv[r] = *(const bf16x8*)(Sp + (size_t)(p0 + pb + r) * Qpad);
#pragma unroll
    for (int r = 0; r < 8; r++)
      for (int j = 0; j < 8; j++)
        acc[j] += __expf(fmaf((float)sv[r][j], idv[j], nid[j]));
  }
  float* zp = Zp + ((size_t)n * NSL + sy) * Qpad + q;
  *(f32x4*)zp = f32x4{acc[0], acc[1], acc[2], acc[3]};
  *(f32x4*)(zp + 4) = f32x4{acc[4], acc[5], acc[6], acc[7]};
}

// ---- reduce: Z[q] = sum_slab Zp ; c[q] = -log(Z)-invd ---- grid (13,8)
__global__ __launch_bounds__(256) void reduce_kernel(
    const float* __restrict__ Zp3, const float* __restrict__ invd3, float* __restrict__ c3,
    const float* __restrict__ Zp4, const float* __restrict__ invd4, float* __restrict__ c4)
{
  int lay = blockIdx.y >> 2, n = blockIdx.y & 3;
  const float *Zp, *invd; float* c; int Qreal, Qpad, NSL;
  if (lay == 0) { Zp = Zp3; invd = invd3; c = c3; Qreal = 3136; Qpad = 3200; NSL = 98; }
  else          { Zp = Zp4; invd = invd4; c = c4; Qreal = 784;  Qpad = 896;  NSL = 49; }
  int q = blockIdx.x * 256 + threadIdx.x;
  if (q >= Qreal) return;
  float s0 = 0.f, s1 = 0.f, s2 = 0.f, s3 = 0.f;
  int sl = 0;
  for (; sl + 4 <= NSL; sl += 4) {
    s0 += Zp[((size_t)n * NSL + sl) * Qpad + q];
    s1 += Zp[((size_t)n * NSL + sl + 1) * Qpad + q];
    s2 += Zp[((size_t)n * NSL + sl + 2) * Qpad + q];
    s3 += Zp[((size_t)n * NSL + sl + 3) * Qpad + q];
  }
  for (; sl < NSL; sl++) s0 += Zp[((size_t)n * NSL + sl) * Qpad + q];
  float s = (s0 + s1) + (s2 + s3);
  c[(size_t)n * Qpad + q] = -logf(s) - invd[(size_t)n * Qpad + q];
}

// ---- rowmax: kmax[p] = exp(max_q (S*invd + c)) ; 8 rows/block;
// exact 1D grid: 1960 blocks ----
__global__ __launch_bounds__(256) void rowmax_kernel(
    const __bf16* __restrict__ S3, const float* __restrict__ invd3,
    const float* __restrict__ c3, float* __restrict__ km3,
    const __bf16* __restrict__ S4, const float* __restrict__ invd4,
    const float* __restrict__ c4, float* __restrict__ km4)
{
  int id = blockIdx.x;
  const __bf16* S; const float *invd, *cc; float* kmax;
  int Qreal, Qpad, Ppad, n, blk;
  if (id < 1568) {
    n = id / 392; blk = id - n * 392;
    S = S3; invd = invd3; cc = c3; kmax = km3; Qreal = 3136; Qpad = 3200; Ppad = 3200;
  } else {
    id -= 1568;
    n = id / 98; blk = id - n * 98;
    S = S4; invd = invd4; cc = c4; kmax = km4; Qreal = 784;  Qpad = 896;  Ppad = 896;
  }
  int p0 = blk * 8;
  const __bf16* Sp = S + ((size_t)n * Ppad + p0) * Qpad;
  const float* idp = invd + (size_t)n * Qpad;
  const float* cp = cc + (size_t)n * Qpad;
  int nq8 = Qreal >> 3;
  float m[8];
#pragma unroll
  for (int r = 0; r < 8; r++) m[r] = -INFINITY;
  for (int i = threadIdx.x; i < nq8; i += 256) {
    f32x4 i0 = *(const f32x4*)(idp + (size_t)i * 8);
    f32x4 i1 = *(const f32x4*)(idp + (size_t)i * 8 + 4);
    f32x4 c0 = *(const f32x4*)(cp + (size_t)i * 8);
    f32x4 c1 = *(const f32x4*)(cp + (size_t)i * 8 + 4);
#pragma unroll
    for (int r = 0; r < 8; r++) {
      bf16x8 sv = *(const bf16x8*)(Sp + (size_t)r * Qpad + (size_t)i * 8);
      for (int j = 0; j < 4; j++)
        m[r] = fmaxf(m[r], fmaf((float)sv[j], i0[j], c0[j]));
      for (int j = 0; j < 4; j++)
        m[r] = fmaxf(m[r], fmaf((float)sv[j + 4], i1[j], c1[j]));
    }
  }
#pragma unroll
  for (int r = 0; r < 8; r++)
    for (int off = 32; off > 0; off >>= 1)
      m[r] = fmaxf(m[r], __shfl_xor(m[r], off, 64));
  __shared__ float red[4][8];
  int w = threadIdx.x >> 6;
  if ((threadIdx.x & 63) == 0)
    for (int r = 0; r < 8; r++) red[w][r] = m[r];
  __syncthreads();
  if (threadIdx.x < 8) {
    int r = threadIdx.x;
    float mr = fmaxf(fmaxf(red[0][r], red[1][r]), fmaxf(red[2][r], red[3][r]));
    kmax[(size_t)n * Ppad + p0 + r] = __expf(mr);
  }
}

// loss = 0.5 * sum_n -log(mean_p kmax3) + 1.0 * sum_n -log(mean_p kmax4)
__global__ void final_kernel(const float* __restrict__ kmax3, const float* __restrict__ kmax4,
                             float* __restrict__ out)
{
  __shared__ float red[256];
  int tid = threadIdx.x;
  float total = 0.f;
  for (int l = 0; l < 2; l++) {
    const float* km = l ? kmax4 : kmax3;
    int P = l ? 784 : 3136;
    int Ppad = l ? 896 : 3200;
    float wgt = l ? 1.0f : 0.5f;
    for (int n = 0; n < 4; n++) {
      float s = 0.f;
      for (int i = tid; i < P; i += 256) s += km[(size_t)n * Ppad + i];
      red[tid] = s;
      __syncthreads();
      for (int st = 128; st > 0; st >>= 1) {
        if (tid < st) red[tid] += red[tid + st];
        __syncthreads();
      }
      if (tid == 0) total += wgt * (-logf(red[0] / (float)P));
      __syncthreads();
    }
  }
  if (tid == 0) out[0] = total;
}

extern "C" void kernel_launch(void* const* d_in, const int* in_sizes, int n_in,
                              void* d_out, int out_size, void* d_ws, size_t ws_size,
                              hipStream_t stream)
{
  const float* gen3 = (const float*)d_in[0];
  const float* tar3 = (const float*)d_in[1];
  const float* gen4 = (const float*)d_in[2];
  const float* tar4 = (const float*)d_in[3];

  char* ws = (char*)d_ws;
  size_t off = 0;
  auto take = [&](size_t bytes) { char* p = ws + off; off += bytes; return p; };

  __bf16* That3 = (__bf16*)take(6553600);       // 4*3200*256*2
  __bf16* Ghat3 = (__bf16*)take(6553600);
  __bf16* That4 = (__bf16*)take(3670016);       // 4*896*512*2
  __bf16* Ghat4 = (__bf16*)take(3670016);
  __bf16* S3    = (__bf16*)take(81920000);      // 4*3200*3200*2
  __bf16* S4    = (__bf16*)take(6422528);       // 4*896*896*2
  float*  Cm3   = (float*) take(2560000);       // 4*50*3200*4
  float*  Cm4   = (float*) take(200704);        // 4*14*896*4
  float*  Zp3   = (float*) take(5017600);       // 4*98*3200*4
  float*  Zp4   = (float*) take(702464);        // 4*49*896*4
  float* invd3  = (float*)take(51200);
  float* c3     = (float*)take(51200);
  float* kmax3  = (float*)take(51200);
  float* invd4  = (float*)take(14336);
  float* c4     = (float*)take(14336);
  float* kmax4  = (float*)take(14336);

  norm_kernel<<<dim3(1, 100, 8), 256, 0, stream>>>(gen3, tar3, Ghat3, That3,
                                                   gen4, tar4, Ghat4, That4);
  gemm_kernel<<<2696, 256, 0, stream>>>(That3, Ghat3, S3, Cm3,
                                        That4, Ghat4, S4, Cm4);
  invd_kernel<<<dim3(13, 8), 256, 0, stream>>>(Cm3, invd3, Cm4, invd4);
  z_kernel<<<980, 256, 0, stream>>>(S3, invd3, Zp3,
                                    S4, invd4, Zp4);
  reduce_kernel<<<dim3(13, 8), 256, 0, stream>>>(Zp3, invd3, c3,
                                                 Zp4, invd4, c4);
  rowmax_kernel<<<1960, 256, 0, stream>>>(S3, invd3, c3, kmax3,
                                          S4, invd4, c4, kmax4);
  final_kernel<<<1, 256, 0, stream>>>(kmax3, kmax4, (float*)d_out);
}

// Round 12
// 206.481 us; speedup vs baseline: 1.2540x; 1.0139x over previous
//
#include <hip/hip_runtime.h>
#include <math.h>

typedef __bf16 bf16x8 __attribute__((ext_vector_type(8)));
typedef float f32x4 __attribute__((ext_vector_type(4)));

#define EPSV 1e-5f
#define GLB(p) ((__attribute__((address_space(1))) void*)(p))
#define LDS(p) ((__attribute__((address_space(3))) void*)(p))

// ---- single-pass norm with LDS-bounced coalesced writes.
// Block owns p-tile x all C. Stats in regs+LDS reduce; normalized bf16 values
// bounce through a 16-KB LDS tile (XOR bank swizzle col^row) and leave as
// fully-contiguous 1-KB-per-wave row stores (the old direct stores scattered
// 16-B granules at stride 512 B -> RFO + 4x write amplification).
// grid (1, 100, 8): z>>2 = layer, z&3 = n.
__global__ __launch_bounds__(256) void norm_kernel(
    const float* __restrict__ g3, const float* __restrict__ t3,
    __bf16* __restrict__ G3, __bf16* __restrict__ T3,
    const float* __restrict__ g4, const float* __restrict__ t4,
    __bf16* __restrict__ G4, __bf16* __restrict__ T4)
{
  __shared__ __attribute__((aligned(16))) char lbuf[16384];
  int lay = blockIdx.z >> 2, n = blockIdx.z & 3;
  const float *gen, *tar; __bf16 *Gh, *Th; int C, P, Ppad, PT, NWORK, NTOT, NG;
  if (lay == 0) { gen = g3; tar = t3; Gh = G3; Th = T3; C = 256; P = 3136; Ppad = 3200; PT = 32; NWORK = 98; NTOT = 100; NG = 8; }
  else          { gen = g4; tar = t4; Gh = G4; Th = T4; C = 512; P = 784;  Ppad = 896;  PT = 16; NWORK = 49; NTOT = 56;  NG = 16; }
  if (blockIdx.y >= (unsigned)NTOT) return;
  int tid = threadIdx.x;
  int pl, cg;
  if (lay == 0) { pl = tid & 31; cg = tid >> 5; }
  else          { pl = tid & 15; cg = tid >> 4; }
  int c0 = cg * 32;

  if (blockIdx.y >= (unsigned)NWORK) {  // zero pad rows (tiny, direct stores ok)
    int p = P + (blockIdx.y - NWORK) * PT + pl;
    if (p < Ppad) {
      __bf16* tp = Th + ((size_t)n * Ppad + p) * C + c0;
      __bf16* gp = Gh + ((size_t)n * Ppad + p) * C + c0;
      bf16x8 z;
      for (int j = 0; j < 8; j++) z[j] = (__bf16)0.f;
      for (int j = 0; j < 32; j += 8) { *(bf16x8*)(tp + j) = z; *(bf16x8*)(gp + j) = z; }
    }
    return;
  }

  int pbase = blockIdx.y * PT;
  int p = pbase + pl;
  const float* tb = tar + (size_t)n * C * P + (size_t)c0 * P + p;
  const float* gb = gen + (size_t)n * C * P + (size_t)c0 * P + p;
  float tv[32], gv[32];
  float st = 0.f, sst = 0.f, sg = 0.f, ssg = 0.f;
#pragma unroll
  for (int j = 0; j < 32; j++) {
    tv[j] = tb[(size_t)j * P];
    gv[j] = gb[(size_t)j * P];
  }
#pragma unroll
  for (int j = 0; j < 32; j++) {
    st += tv[j]; sst += tv[j] * tv[j];
    sg += gv[j]; ssg += gv[j] * gv[j];
  }
  __shared__ f32x4 red[16][32];
  red[cg][pl] = f32x4{st, sst, sg, ssg};
  __syncthreads();
  for (int h = NG >> 1; h > 0; h >>= 1) {
    if (cg < h) {
      f32x4 a = red[cg][pl], b = red[cg + h][pl];
      red[cg][pl] = f32x4{a[0] + b[0], a[1] + b[1], a[2] + b[2], a[3] + b[3]};
    }
    __syncthreads();
  }
  f32x4 s = red[0][pl];
  float m = s[0] / (float)C;
  float vt = s[1] - s[0] * s[0] / (float)C;
  float vg = s[3] - 2.f * m * s[2] + (float)C * m * m;
  float it = rsqrtf(fmaxf(vt, 1e-30f));
  float ig = rsqrtf(fmaxf(vg, 1e-30f));

  int w = tid >> 6, l = tid & 63;
  for (int arr = 0; arr < 2; arr++) {
    float sc = arr ? ig : it;
    __syncthreads();  // protect previous array's LDS reads
    if (lay == 0) {
#pragma unroll
      for (int k = 0; k < 4; k++) {
        int col = cg * 4 + k;
        int colp = col ^ pl;  // pl 0..31, col 0..31
        bf16x8 v;
        for (int j = 0; j < 8; j++) {
          float x = arr ? gv[k * 8 + j] : tv[k * 8 + j];
          v[j] = (__bf16)((x - m) * sc);
        }
        *(bf16x8*)(lbuf + pl * 512 + colp * 16) = v;
      }
    } else {
#pragma unroll
      for (int k = 0; k < 4; k++) {
        int col = cg * 4 + k;           // 0..63
        int colp = col ^ pl;            // pl 0..15, flips low 4 bits
        bf16x8 v;
        for (int j = 0; j < 8; j++) {
          float x = arr ? gv[k * 8 + j] : tv[k * 8 + j];
          v[j] = (__bf16)((x - m) * sc);
        }
        *(bf16x8*)(lbuf + pl * 1024 + colp * 16) = v;
      }
    }
    __syncthreads();
    __bf16* dst = (arr ? Gh : Th) + ((size_t)n * Ppad + pbase) * C;
    if (lay == 0) {
#pragma unroll
      for (int it2 = 0; it2 < 4; it2++) {
        int row = w * 8 + it2 * 2 + (l >> 5);
        int col = l & 31;
        int colp = col ^ row;
        bf16x8 v = *(const bf16x8*)(lbuf + row * 512 + colp * 16);
        *(bf16x8*)(dst + (size_t)row * 256 + col * 8) = v;
      }
    } else {
#pragma unroll
      for (int it2 = 0; it2 < 4; it2++) {
        int row = w * 4 + it2;
        int col = l;
        int colp = col ^ (row & 15);
        bf16x8 v = *(const bf16x8*)(lbuf + row * 1024 + colp * 16);
        *(bf16x8*)(dst + (size_t)row * 512 + col * 8) = v;
      }
    }
  }
}

// ---- GEMM: 128x128 tile, BK=64 per barrier-phase (two proven-swizzle BK=32
// LDS buffers -> 8 load_lds in flight, one barrier pair / 64 K), lb(256,3),
// conflict-free 296-B epilogue bounce, NON-TEMPORAL S stores (A/B evidence
// R8 vs R11: nt beats cached on both gemm dur and total), colmax partial
// stores (NO atomics): Cm[n][pt*2+rowhalf][q]. ----
__global__ __launch_bounds__(256, 3) void gemm_kernel(
    const __bf16* __restrict__ A3, const __bf16* __restrict__ B3,
    __bf16* __restrict__ So3, float* __restrict__ Cm3,
    const __bf16* __restrict__ A4, const __bf16* __restrict__ B4,
    __bf16* __restrict__ So4, float* __restrict__ Cm4)
{
  __shared__ __attribute__((aligned(16))) char smem[37888];

  int id = blockIdx.x;
  const __bf16 *A, *B; __bf16* S; float* Cm;
  int C, Ppad, Qpad, Preal, NT, n, t;
  if (id < 2500) {
    n = id / 625; t = id - n * 625;
    A = A3; B = B3; S = So3; Cm = Cm3; C = 256; Ppad = 3200; Qpad = 3200; Preal = 3136; NT = 25;
  } else {
    id -= 2500;
    n = id / 49; t = id - n * 49;
    A = A4; B = B4; S = So4; Cm = Cm4; C = 512; Ppad = 896;  Qpad = 896;  Preal = 784;  NT = 7;
  }
  int bpb = NT * 8;
  int b = t / bpb, r = t - b * bpb;
  int rem = NT - b * 8;
  int h = rem < 8 ? rem : 8;
  int pt = b * 8 + r % h, qt = r / h;
  int p0 = pt * 128, q0 = qt * 128;

  int tid = threadIdx.x;
  int w = tid >> 6, lane = tid & 63;
  int lm = lane & 15, lq = lane >> 4;
  int wrow = (w >> 1) * 64, wcol = (w & 1) * 64;

  int srow = tid >> 2;
  int scol = ((tid & 3) ^ ((tid >> 3) & 3)) * 8;
  const __bf16* gA = A + ((size_t)n * Ppad + p0 + srow) * C + scol;
  const __bf16* gB = B + ((size_t)n * Qpad + q0 + srow) * C + scol;
  size_t rowoff = (size_t)64 * C;

  int sl = lq ^ ((lm >> 1) & 3);
  int aoff = (wrow + lm) * 64 + sl * 16;
  int boff = (wcol + lm) * 64 + sl * 16;

  f32x4 acc[4][4];
  for (int i = 0; i < 4; i++)
    for (int j = 0; j < 4; j++)
      acc[i][j] = f32x4{0.f, 0.f, 0.f, 0.f};

  for (int k0 = 0; k0 < C; k0 += 64) {
    __syncthreads();
#pragma unroll
    for (int sub = 0; sub < 2; sub++) {
      int kk = k0 + sub * 32;
      char* a = smem + sub * 8192 + w * 1024;
      char* bb = smem + 16384 + sub * 8192 + w * 1024;
      __builtin_amdgcn_global_load_lds(GLB(gA + kk), LDS(a), 16, 0, 0);
      __builtin_amdgcn_global_load_lds(GLB(gA + rowoff + kk), LDS(a + 4096), 16, 0, 0);
      __builtin_amdgcn_global_load_lds(GLB(gB + kk), LDS(bb), 16, 0, 0);
      __builtin_amdgcn_global_load_lds(GLB(gB + rowoff + kk), LDS(bb + 4096), 16, 0, 0);
    }
    __syncthreads();
#pragma unroll
    for (int sub = 0; sub < 2; sub++) {
      const char* ab = smem + sub * 8192;
      const char* bb = smem + 16384 + sub * 8192;
      bf16x8 af[4], bf[4];
      for (int i = 0; i < 4; i++) af[i] = *(const bf16x8*)(ab + aoff + i * 1024);
      for (int j = 0; j < 4; j++) bf[j] = *(const bf16x8*)(bb + boff + j * 1024);
      for (int i = 0; i < 4; i++)
        for (int j = 0; j < 4; j++)
          acc[i][j] = __builtin_amdgcn_mfma_f32_16x16x32_bf16(af[i], bf[j], acc[i][j], 0, 0, 0);
    }
  }

  float cm[4] = {-INFINITY, -INFINITY, -INFINITY, -INFINITY};
  for (int i = 0; i < 4; i++)
    for (int j = 0; j < 4; j++)
      for (int ri = 0; ri < 4; ri++) {
        int pr = p0 + wrow + i * 16 + lq * 4 + ri;
        if (pr < Preal) cm[j] = fmaxf(cm[j], (float)(__bf16)acc[i][j][ri]);
      }

  __syncthreads();
  for (int i = 0; i < 4; i++) {
    for (int j = 0; j < 4; j++) {
      int row = wrow + i * 16 + lq * 4;
      int col = wcol + j * 16 + lm;
      for (int ri = 0; ri < 4; ri++)
        *(__bf16*)(smem + (row + ri) * 296 + col * 2) = (__bf16)acc[i][j][ri];
    }
  }
  __syncthreads();
  __bf16* Sb = S + (size_t)n * Ppad * Qpad;
  int rr = tid >> 4, cc8 = (tid & 15) * 8;
  for (int r8 = 0; r8 < 8; r8++) {
    int row = r8 * 16 + rr;
    bf16x8 v = *(const bf16x8*)(smem + row * 296 + cc8 * 2);
    __builtin_nontemporal_store(v, (bf16x8*)(Sb + (size_t)(p0 + row) * Qpad + q0 + cc8));
  }

  for (int j = 0; j < 4; j++) {
    float v = cm[j];
    v = fmaxf(v, __shfl_xor(v, 16, 64));
    v = fmaxf(v, __shfl_xor(v, 32, 64));
    if (lq == 0) {
      int qc = q0 + wcol + j * 16 + lm;
      Cm[((size_t)n * NT * 2 + pt * 2 + (w >> 1)) * Qpad + qc] = v;
    }
  }
}

// ---- invd: reduce Cm partials -> invd[q] = 1/(0.5*(1-colmax)+eps) ----
__global__ __launch_bounds__(256) void invd_kernel(
    const float* __restrict__ Cm3, float* __restrict__ invd3,
    const float* __restrict__ Cm4, float* __restrict__ invd4)
{
  int lay = blockIdx.y >> 2, n = blockIdx.y & 3;
  const float* Cm; float* invd; int Qreal, Qpad, NP;
  if (lay == 0) { Cm = Cm3; invd = invd3; Qreal = 3136; Qpad = 3200; NP = 50; }
  else          { Cm = Cm4; invd = invd4; Qreal = 784;  Qpad = 896;  NP = 14; }
  int q = blockIdx.x * 256 + threadIdx.x;
  if (q >= Qreal) return;
  float mx = -INFINITY;
  for (int i = 0; i < NP; i++)
    mx = fmaxf(mx, Cm[((size_t)n * NP + i) * Qpad + q]);
  float d = 0.5f * (1.f - mx) + EPSV;
  invd[(size_t)n * Qpad + q] = 1.f / d;
}

// ---- z partials: block = q-tile(2048) x p-slab(32/16); NO atomics;
// 8 row-loads in flight. exact 1D grid: 980 blocks ----
__global__ __launch_bounds__(256) void z_kernel(
    const __bf16* __restrict__ S3, const float* __restrict__ invd3, float* __restrict__ Zp3,
    const __bf16* __restrict__ S4, const float* __restrict__ invd4, float* __restrict__ Zp4)
{
  int id = blockIdx.x;
  const __bf16* S; const float* invd; float* Zp;
  int Ppad, Qreal, Qpad, NSL, SLAB, n, qx, sy;
  if (id < 784) {
    n = id / 196; int r = id - n * 196; sy = r >> 1; qx = r & 1;
    S = S3; invd = invd3; Zp = Zp3; Ppad = 3200; Qreal = 3136; Qpad = 3200; NSL = 98; SLAB = 32;
  } else {
    id -= 784;
    n = id / 49; sy = id - n * 49; qx = 0;
    S = S4; invd = invd4; Zp = Zp4; Ppad = 896;  Qreal = 784;  Qpad = 896;  NSL = 49; SLAB = 16;
  }
  int q = (qx * 256 + threadIdx.x) * 8;
  if (q >= Qreal) return;
  float idv[8], nid[8];
  const float* ip = invd + (size_t)n * Qpad + q;
#pragma unroll
  for (int j = 0; j < 8; j++) {
    idv[j] = ip[j];
    nid[j] = -idv[j];
  }
  int p0 = sy * SLAB;
  const __bf16* Sp = S + (size_t)n * Ppad * Qpad + q;
  float acc[8] = {0.f, 0.f, 0.f, 0.f, 0.f, 0.f, 0.f, 0.f};
  for (int pb = 0; pb < SLAB; pb += 8) {
    bf16x8 sv[8];
#pragma unroll
    for (int r = 0; r < 8; r++)
      sv[r] = *(const bf16x8*)(Sp + (size_t)(p0 + pb + r) * Qpad);
#pragma unroll
    for (int r = 0; r < 8; r++)
      for (int j = 0; j < 8; j++)
        acc[j] += __expf(fmaf((float)sv[r][j], idv[j], nid[j]));
  }
  float* zp = Zp + ((size_t)n * NSL + sy) * Qpad + q;
  *(f32x4*)zp = f32x4{acc[0], acc[1], acc[2], acc[3]};
  *(f32x4*)(zp + 4) = f32x4{acc[4], acc[5], acc[6], acc[7]};
}

// ---- reduce: Z[q] = sum_slab Zp ; c[q] = -log(Z)-invd ---- grid (13,8)
__global__ __launch_bounds__(256) void reduce_kernel(
    const float* __restrict__ Zp3, const float* __restrict__ invd3, float* __restrict__ c3,
    const float* __restrict__ Zp4, const float* __restrict__ invd4, float* __restrict__ c4)
{
  int lay = blockIdx.y >> 2, n = blockIdx.y & 3;
  const float *Zp, *invd; float* c; int Qreal, Qpad, NSL;
  if (lay == 0) { Zp = Zp3; invd = invd3; c = c3; Qreal = 3136; Qpad = 3200; NSL = 98; }
  else          { Zp = Zp4; invd = invd4; c = c4; Qreal = 784;  Qpad = 896;  NSL = 49; }
  int q = blockIdx.x * 256 + threadIdx.x;
  if (q >= Qreal) return;
  float s0 = 0.f, s1 = 0.f, s2 = 0.f, s3 = 0.f;
  int sl = 0;
  for (; sl + 4 <= NSL; sl += 4) {
    s0 += Zp[((size_t)n * NSL + sl) * Qpad + q];
    s1 += Zp[((size_t)n * NSL + sl + 1) * Qpad + q];
    s2 += Zp[((size_t)n * NSL + sl + 2) * Qpad + q];
    s3 += Zp[((size_t)n * NSL + sl + 3) * Qpad + q];
  }
  for (; sl < NSL; sl++) s0 += Zp[((size_t)n * NSL + sl) * Qpad + q];
  float s = (s0 + s1) + (s2 + s3);
  c[(size_t)n * Qpad + q] = -logf(s) - invd[(size_t)n * Qpad + q];
}

// ---- rowmax: kmax[p] = exp(max_q (S*invd + c)) ; 8 rows/block;
// exact 1D grid: 1960 blocks ----
__global__ __launch_bounds__(256) void rowmax_kernel(
    const __bf16* __restrict__ S3, const float* __restrict__ invd3,
    const float* __restrict__ c3, float* __restrict__ km3,
    const __bf16* __restrict__ S4, const float* __restrict__ invd4,
    const float* __restrict__ c4, float* __restrict__ km4)
{
  int id = blockIdx.x;
  const __bf16* S; const float *invd, *cc; float* kmax;
  int Qreal, Qpad, Ppad, n, blk;
  if (id < 1568) {
    n = id / 392; blk = id - n * 392;
    S = S3; invd = invd3; cc = c3; kmax = km3; Qreal = 3136; Qpad = 3200; Ppad = 3200;
  } else {
    id -= 1568;
    n = id / 98; blk = id - n * 98;
    S = S4; invd = invd4; cc = c4; kmax = km4; Qreal = 784;  Qpad = 896;  Ppad = 896;
  }
  int p0 = blk * 8;
  const __bf16* Sp = S + ((size_t)n * Ppad + p0) * Qpad;
  const float* idp = invd + (size_t)n * Qpad;
  const float* cp = cc + (size_t)n * Qpad;
  int nq8 = Qreal >> 3;
  float m[8];
#pragma unroll
  for (int r = 0; r < 8; r++) m[r] = -INFINITY;
  for (int i = threadIdx.x; i < nq8; i += 256) {
    f32x4 i0 = *(const f32x4*)(idp + (size_t)i * 8);
    f32x4 i1 = *(const f32x4*)(idp + (size_t)i * 8 + 4);
    f32x4 c0 = *(const f32x4*)(cp + (size_t)i * 8);
    f32x4 c1 = *(const f32x4*)(cp + (size_t)i * 8 + 4);
#pragma unroll
    for (int r = 0; r < 8; r++) {
      bf16x8 sv = *(const bf16x8*)(Sp + (size_t)r * Qpad + (size_t)i * 8);
      for (int j = 0; j < 4; j++)
        m[r] = fmaxf(m[r], fmaf((float)sv[j], i0[j], c0[j]));
      for (int j = 0; j < 4; j++)
        m[r] = fmaxf(m[r], fmaf((float)sv[j + 4], i1[j], c1[j]));
    }
  }
#pragma unroll
  for (int r = 0; r < 8; r++)
    for (int off = 32; off > 0; off >>= 1)
      m[r] = fmaxf(m[r], __shfl_xor(m[r], off, 64));
  __shared__ float red[4][8];
  int w = threadIdx.x >> 6;
  if ((threadIdx.x & 63) == 0)
    for (int r = 0; r < 8; r++) red[w][r] = m[r];
  __syncthreads();
  if (threadIdx.x < 8) {
    int r = threadIdx.x;
    float mr = fmaxf(fmaxf(red[0][r], red[1][r]), fmaxf(red[2][r], red[3][r]));
    kmax[(size_t)n * Ppad + p0 + r] = __expf(mr);
  }
}

// loss = 0.5 * sum_n -log(mean_p kmax3) + 1.0 * sum_n -log(mean_p kmax4)
__global__ void final_kernel(const float* __restrict__ kmax3, const float* __restrict__ kmax4,
                             float* __restrict__ out)
{
  __shared__ float red[256];
  int tid = threadIdx.x;
  float total = 0.f;
  for (int l = 0; l < 2; l++) {
    const float* km = l ? kmax4 : kmax3;
    int P = l ? 784 : 3136;
    int Ppad = l ? 896 : 3200;
    float wgt = l ? 1.0f : 0.5f;
    for (int n = 0; n < 4; n++) {
      float s = 0.f;
      for (int i = tid; i < P; i += 256) s += km[(size_t)n * Ppad + i];
      red[tid] = s;
      __syncthreads();
      for (int st = 128; st > 0; st >>= 1) {
        if (tid < st) red[tid] += red[tid + st];
        __syncthreads();
      }
      if (tid == 0) total += wgt * (-logf(red[0] / (float)P));
      __syncthreads();
    }
  }
  if (tid == 0) out[0] = total;
}

extern "C" void kernel_launch(void* const* d_in, const int* in_sizes, int n_in,
                              void* d_out, int out_size, void* d_ws, size_t ws_size,
                              hipStream_t stream)
{
  const float* gen3 = (const float*)d_in[0];
  const float* tar3 = (const float*)d_in[1];
  const float* gen4 = (const float*)d_in[2];
  const float* tar4 = (const float*)d_in[3];

  char* ws = (char*)d_ws;
  size_t off = 0;
  auto take = [&](size_t bytes) { char* p = ws + off; off += bytes; return p; };

  __bf16* That3 = (__bf16*)take(6553600);       // 4*3200*256*2
  __bf16* Ghat3 = (__bf16*)take(6553600);
  __bf16* That4 = (__bf16*)take(3670016);       // 4*896*512*2
  __bf16* Ghat4 = (__bf16*)take(3670016);
  __bf16* S3    = (__bf16*)take(81920000);      // 4*3200*3200*2
  __bf16* S4    = (__bf16*)take(6422528);       // 4*896*896*2
  float*  Cm3   = (float*) take(2560000);       // 4*50*3200*4
  float*  Cm4   = (float*) take(200704);        // 4*14*896*4
  float*  Zp3   = (float*) take(5017600);       // 4*98*3200*4
  float*  Zp4   = (float*) take(702464);        // 4*49*896*4
  float* invd3  = (float*)take(51200);
  float* c3     = (float*)take(51200);
  float* kmax3  = (float*)take(51200);
  float* invd4  = (float*)take(14336);
  float* c4     = (float*)take(14336);
  float* kmax4  = (float*)take(14336);

  norm_kernel<<<dim3(1, 100, 8), 256, 0, stream>>>(gen3, tar3, Ghat3, That3,
                                                   gen4, tar4, Ghat4, That4);
  gemm_kernel<<<2696, 256, 0, stream>>>(That3, Ghat3, S3, Cm3,
                                        That4, Ghat4, S4, Cm4);
  invd_kernel<<<dim3(13, 8), 256, 0, stream>>>(Cm3, invd3, Cm4, invd4);
  z_kernel<<<980, 256, 0, stream>>>(S3, invd3, Zp3,
                                    S4, invd4, Zp4);
  reduce_kernel<<<dim3(13, 8), 256, 0, stream>>>(Zp3, invd3, c3,
                                                 Zp4, invd4, c4);
  rowmax_kernel<<<1960, 256, 0, stream>>>(S3, invd3, c3, kmax3,
                                          S4, invd4, c4, kmax4);
  final_kernel<<<1, 256, 0, stream>>>(kmax3, kmax4, (float*)d_out);
}

// Round 13
// 205.737 us; speedup vs baseline: 1.2585x; 1.0036x over previous
//
#include <hip/hip_runtime.h>
#include <math.h>

typedef __bf16 bf16x8 __attribute__((ext_vector_type(8)));
typedef float f32x4 __attribute__((ext_vector_type(4)));
typedef float f32x2 __attribute__((ext_vector_type(2)));

#define EPSV 1e-5f
#define GLB(p) ((__attribute__((address_space(1))) void*)(p))
#define LDS(p) ((__attribute__((address_space(3))) void*)(p))

// ---- single-pass norm with LDS-bounced coalesced writes. ----
// grid (1, 100, 8): z>>2 = layer, z&3 = n.
__global__ __launch_bounds__(256) void norm_kernel(
    const float* __restrict__ g3, const float* __restrict__ t3,
    __bf16* __restrict__ G3, __bf16* __restrict__ T3,
    const float* __restrict__ g4, const float* __restrict__ t4,
    __bf16* __restrict__ G4, __bf16* __restrict__ T4)
{
  __shared__ __attribute__((aligned(16))) char lbuf[16384];
  int lay = blockIdx.z >> 2, n = blockIdx.z & 3;
  const float *gen, *tar; __bf16 *Gh, *Th; int C, P, Ppad, PT, NWORK, NTOT, NG;
  if (lay == 0) { gen = g3; tar = t3; Gh = G3; Th = T3; C = 256; P = 3136; Ppad = 3200; PT = 32; NWORK = 98; NTOT = 100; NG = 8; }
  else          { gen = g4; tar = t4; Gh = G4; Th = T4; C = 512; P = 784;  Ppad = 896;  PT = 16; NWORK = 49; NTOT = 56;  NG = 16; }
  if (blockIdx.y >= (unsigned)NTOT) return;
  int tid = threadIdx.x;
  int pl, cg;
  if (lay == 0) { pl = tid & 31; cg = tid >> 5; }
  else          { pl = tid & 15; cg = tid >> 4; }
  int c0 = cg * 32;

  if (blockIdx.y >= (unsigned)NWORK) {  // zero pad rows
    int p = P + (blockIdx.y - NWORK) * PT + pl;
    if (p < Ppad) {
      __bf16* tp = Th + ((size_t)n * Ppad + p) * C + c0;
      __bf16* gp = Gh + ((size_t)n * Ppad + p) * C + c0;
      bf16x8 z;
      for (int j = 0; j < 8; j++) z[j] = (__bf16)0.f;
      for (int j = 0; j < 32; j += 8) { *(bf16x8*)(tp + j) = z; *(bf16x8*)(gp + j) = z; }
    }
    return;
  }

  int pbase = blockIdx.y * PT;
  int p = pbase + pl;
  const float* tb = tar + (size_t)n * C * P + (size_t)c0 * P + p;
  const float* gb = gen + (size_t)n * C * P + (size_t)c0 * P + p;
  float tv[32], gv[32];
  float st = 0.f, sst = 0.f, sg = 0.f, ssg = 0.f;
#pragma unroll
  for (int j = 0; j < 32; j++) {
    tv[j] = tb[(size_t)j * P];
    gv[j] = gb[(size_t)j * P];
  }
#pragma unroll
  for (int j = 0; j < 32; j++) {
    st += tv[j]; sst += tv[j] * tv[j];
    sg += gv[j]; ssg += gv[j] * gv[j];
  }
  __shared__ f32x4 red[16][32];
  red[cg][pl] = f32x4{st, sst, sg, ssg};
  __syncthreads();
  for (int h = NG >> 1; h > 0; h >>= 1) {
    if (cg < h) {
      f32x4 a = red[cg][pl], b = red[cg + h][pl];
      red[cg][pl] = f32x4{a[0] + b[0], a[1] + b[1], a[2] + b[2], a[3] + b[3]};
    }
    __syncthreads();
  }
  f32x4 s = red[0][pl];
  float m = s[0] / (float)C;
  float vt = s[1] - s[0] * s[0] / (float)C;
  float vg = s[3] - 2.f * m * s[2] + (float)C * m * m;
  float it = rsqrtf(fmaxf(vt, 1e-30f));
  float ig = rsqrtf(fmaxf(vg, 1e-30f));

  int w = tid >> 6, l = tid & 63;
  for (int arr = 0; arr < 2; arr++) {
    float sc = arr ? ig : it;
    __syncthreads();
    if (lay == 0) {
#pragma unroll
      for (int k = 0; k < 4; k++) {
        int col = cg * 4 + k;
        int colp = col ^ pl;
        bf16x8 v;
        for (int j = 0; j < 8; j++) {
          float x = arr ? gv[k * 8 + j] : tv[k * 8 + j];
          v[j] = (__bf16)((x - m) * sc);
        }
        *(bf16x8*)(lbuf + pl * 512 + colp * 16) = v;
      }
    } else {
#pragma unroll
      for (int k = 0; k < 4; k++) {
        int col = cg * 4 + k;
        int colp = col ^ pl;
        bf16x8 v;
        for (int j = 0; j < 8; j++) {
          float x = arr ? gv[k * 8 + j] : tv[k * 8 + j];
          v[j] = (__bf16)((x - m) * sc);
        }
        *(bf16x8*)(lbuf + pl * 1024 + colp * 16) = v;
      }
    }
    __syncthreads();
    __bf16* dst = (arr ? Gh : Th) + ((size_t)n * Ppad + pbase) * C;
    if (lay == 0) {
#pragma unroll
      for (int it2 = 0; it2 < 4; it2++) {
        int row = w * 8 + it2 * 2 + (l >> 5);
        int col = l & 31;
        int colp = col ^ row;
        bf16x8 v = *(const bf16x8*)(lbuf + row * 512 + colp * 16);
        *(bf16x8*)(dst + (size_t)row * 256 + col * 8) = v;
      }
    } else {
#pragma unroll
      for (int it2 = 0; it2 < 4; it2++) {
        int row = w * 4 + it2;
        int col = l;
        int colp = col ^ (row & 15);
        bf16x8 v = *(const bf16x8*)(lbuf + row * 1024 + colp * 16);
        *(bf16x8*)(dst + (size_t)row * 512 + col * 8) = v;
      }
    }
  }
}

// ---- GEMM: frozen R12 config (BK=64 phases, lb(256,3), nt S stores, Cm). ----
__global__ __launch_bounds__(256, 3) void gemm_kernel(
    const __bf16* __restrict__ A3, const __bf16* __restrict__ B3,
    __bf16* __restrict__ So3, float* __restrict__ Cm3,
    const __bf16* __restrict__ A4, const __bf16* __restrict__ B4,
    __bf16* __restrict__ So4, float* __restrict__ Cm4)
{
  __shared__ __attribute__((aligned(16))) char smem[37888];

  int id = blockIdx.x;
  const __bf16 *A, *B; __bf16* S; float* Cm;
  int C, Ppad, Qpad, Preal, NT, n, t;
  if (id < 2500) {
    n = id / 625; t = id - n * 625;
    A = A3; B = B3; S = So3; Cm = Cm3; C = 256; Ppad = 3200; Qpad = 3200; Preal = 3136; NT = 25;
  } else {
    id -= 2500;
    n = id / 49; t = id - n * 49;
    A = A4; B = B4; S = So4; Cm = Cm4; C = 512; Ppad = 896;  Qpad = 896;  Preal = 784;  NT = 7;
  }
  int bpb = NT * 8;
  int b = t / bpb, r = t - b * bpb;
  int rem = NT - b * 8;
  int h = rem < 8 ? rem : 8;
  int pt = b * 8 + r % h, qt = r / h;
  int p0 = pt * 128, q0 = qt * 128;

  int tid = threadIdx.x;
  int w = tid >> 6, lane = tid & 63;
  int lm = lane & 15, lq = lane >> 4;
  int wrow = (w >> 1) * 64, wcol = (w & 1) * 64;

  int srow = tid >> 2;
  int scol = ((tid & 3) ^ ((tid >> 3) & 3)) * 8;
  const __bf16* gA = A + ((size_t)n * Ppad + p0 + srow) * C + scol;
  const __bf16* gB = B + ((size_t)n * Qpad + q0 + srow) * C + scol;
  size_t rowoff = (size_t)64 * C;

  int sl = lq ^ ((lm >> 1) & 3);
  int aoff = (wrow + lm) * 64 + sl * 16;
  int boff = (wcol + lm) * 64 + sl * 16;

  f32x4 acc[4][4];
  for (int i = 0; i < 4; i++)
    for (int j = 0; j < 4; j++)
      acc[i][j] = f32x4{0.f, 0.f, 0.f, 0.f};

  for (int k0 = 0; k0 < C; k0 += 64) {
    __syncthreads();
#pragma unroll
    for (int sub = 0; sub < 2; sub++) {
      int kk = k0 + sub * 32;
      char* a = smem + sub * 8192 + w * 1024;
      char* bb = smem + 16384 + sub * 8192 + w * 1024;
      __builtin_amdgcn_global_load_lds(GLB(gA + kk), LDS(a), 16, 0, 0);
      __builtin_amdgcn_global_load_lds(GLB(gA + rowoff + kk), LDS(a + 4096), 16, 0, 0);
      __builtin_amdgcn_global_load_lds(GLB(gB + kk), LDS(bb), 16, 0, 0);
      __builtin_amdgcn_global_load_lds(GLB(gB + rowoff + kk), LDS(bb + 4096), 16, 0, 0);
    }
    __syncthreads();
#pragma unroll
    for (int sub = 0; sub < 2; sub++) {
      const char* ab = smem + sub * 8192;
      const char* bb = smem + 16384 + sub * 8192;
      bf16x8 af[4], bf[4];
      for (int i = 0; i < 4; i++) af[i] = *(const bf16x8*)(ab + aoff + i * 1024);
      for (int j = 0; j < 4; j++) bf[j] = *(const bf16x8*)(bb + boff + j * 1024);
      for (int i = 0; i < 4; i++)
        for (int j = 0; j < 4; j++)
          acc[i][j] = __builtin_amdgcn_mfma_f32_16x16x32_bf16(af[i], bf[j], acc[i][j], 0, 0, 0);
    }
  }

  float cm[4] = {-INFINITY, -INFINITY, -INFINITY, -INFINITY};
  for (int i = 0; i < 4; i++)
    for (int j = 0; j < 4; j++)
      for (int ri = 0; ri < 4; ri++) {
        int pr = p0 + wrow + i * 16 + lq * 4 + ri;
        if (pr < Preal) cm[j] = fmaxf(cm[j], (float)(__bf16)acc[i][j][ri]);
      }

  __syncthreads();
  for (int i = 0; i < 4; i++) {
    for (int j = 0; j < 4; j++) {
      int row = wrow + i * 16 + lq * 4;
      int col = wcol + j * 16 + lm;
      for (int ri = 0; ri < 4; ri++)
        *(__bf16*)(smem + (row + ri) * 296 + col * 2) = (__bf16)acc[i][j][ri];
    }
  }
  __syncthreads();
  __bf16* Sb = S + (size_t)n * Ppad * Qpad;
  int rr = tid >> 4, cc8 = (tid & 15) * 8;
  for (int r8 = 0; r8 < 8; r8++) {
    int row = r8 * 16 + rr;
    bf16x8 v = *(const bf16x8*)(smem + row * 296 + cc8 * 2);
    __builtin_nontemporal_store(v, (bf16x8*)(Sb + (size_t)(p0 + row) * Qpad + q0 + cc8));
  }

  for (int j = 0; j < 4; j++) {
    float v = cm[j];
    v = fmaxf(v, __shfl_xor(v, 16, 64));
    v = fmaxf(v, __shfl_xor(v, 32, 64));
    if (lq == 0) {
      int qc = q0 + wcol + j * 16 + lm;
      Cm[((size_t)n * NT * 2 + pt * 2 + (w >> 1)) * Qpad + qc] = v;
    }
  }
}

// ---- invd: reduce Cm partials -> invd[q] ----
__global__ __launch_bounds__(256) void invd_kernel(
    const float* __restrict__ Cm3, float* __restrict__ invd3,
    const float* __restrict__ Cm4, float* __restrict__ invd4)
{
  int lay = blockIdx.y >> 2, n = blockIdx.y & 3;
  const float* Cm; float* invd; int Qreal, Qpad, NP;
  if (lay == 0) { Cm = Cm3; invd = invd3; Qreal = 3136; Qpad = 3200; NP = 50; }
  else          { Cm = Cm4; invd = invd4; Qreal = 784;  Qpad = 896;  NP = 14; }
  int q = blockIdx.x * 256 + threadIdx.x;
  if (q >= Qreal) return;
  float mx = -INFINITY;
  for (int i = 0; i < NP; i++)
    mx = fmaxf(mx, Cm[((size_t)n * NP + i) * Qpad + q]);
  float d = 0.5f * (1.f - mx) + EPSV;
  invd[(size_t)n * Qpad + q] = 1.f / d;
}

// ---- z partials, compile-time sizes -> full unroll + hoisted nt loads ----
template<int SLAB, int NSL, int PPAD, int QPAD, int QREAL>
__device__ __forceinline__ void z_body(
    const __bf16* __restrict__ S, const float* __restrict__ invd,
    float* __restrict__ Zp, int n, int sy, int qx, int tid)
{
  int q = (qx * 256 + tid) * 8;
  if (q >= QREAL) return;
  float idv[8], nid[8];
  const float* ip = invd + (size_t)n * QPAD + q;
#pragma unroll
  for (int j = 0; j < 8; j++) { idv[j] = ip[j]; nid[j] = -idv[j]; }
  int p0 = sy * SLAB;
  const __bf16* Sp = S + (size_t)n * PPAD * QPAD + q;
  float acc[8] = {0.f, 0.f, 0.f, 0.f, 0.f, 0.f, 0.f, 0.f};
#pragma unroll
  for (int pb = 0; pb < SLAB; pb += 8) {
    bf16x8 sv[8];
#pragma unroll
    for (int r = 0; r < 8; r++)
      sv[r] = __builtin_nontemporal_load((const bf16x8*)(Sp + (size_t)(p0 + pb + r) * QPAD));
#pragma unroll
    for (int r = 0; r < 8; r++)
#pragma unroll
      for (int j = 0; j < 8; j++)
        acc[j] += __expf(fmaf((float)sv[r][j], idv[j], nid[j]));
  }
  float* zp = Zp + ((size_t)n * NSL + sy) * QPAD + q;
  *(f32x4*)zp = f32x4{acc[0], acc[1], acc[2], acc[3]};
  *(f32x4*)(zp + 4) = f32x4{acc[4], acc[5], acc[6], acc[7]};
}

// exact 1D grid: 980 blocks
__global__ __launch_bounds__(256) void z_kernel(
    const __bf16* __restrict__ S3, const float* __restrict__ invd3, float* __restrict__ Zp3,
    const __bf16* __restrict__ S4, const float* __restrict__ invd4, float* __restrict__ Zp4)
{
  int id = blockIdx.x;
  if (id < 784) {
    int n = id / 196, r = id - n * 196;
    z_body<32, 98, 3200, 3200, 3136>(S3, invd3, Zp3, n, r >> 1, r & 1, threadIdx.x);
  } else {
    id -= 784;
    int n = id / 49, sy = id - n * 49;
    z_body<16, 49, 896, 896, 784>(S4, invd4, Zp4, n, sy, 0, threadIdx.x);
  }
}

// ---- reduce: Z[q] = sum_slab Zp ; ic[q] = (invd, -logZ-invd) interleaved ----
__global__ __launch_bounds__(256) void reduce_kernel(
    const float* __restrict__ Zp3, const float* __restrict__ invd3, float* __restrict__ ic3,
    const float* __restrict__ Zp4, const float* __restrict__ invd4, float* __restrict__ ic4)
{
  int lay = blockIdx.y >> 2, n = blockIdx.y & 3;
  const float *Zp, *invd; float* ic; int Qreal, Qpad, NSL;
  if (lay == 0) { Zp = Zp3; invd = invd3; ic = ic3; Qreal = 3136; Qpad = 3200; NSL = 98; }
  else          { Zp = Zp4; invd = invd4; ic = ic4; Qreal = 784;  Qpad = 896;  NSL = 49; }
  int q = blockIdx.x * 256 + threadIdx.x;
  if (q >= Qreal) return;
  float s0 = 0.f, s1 = 0.f, s2 = 0.f, s3 = 0.f;
  int sl = 0;
  for (; sl + 4 <= NSL; sl += 4) {
    s0 += Zp[((size_t)n * NSL + sl) * Qpad + q];
    s1 += Zp[((size_t)n * NSL + sl + 1) * Qpad + q];
    s2 += Zp[((size_t)n * NSL + sl + 2) * Qpad + q];
    s3 += Zp[((size_t)n * NSL + sl + 3) * Qpad + q];
  }
  for (; sl < NSL; sl++) s0 += Zp[((size_t)n * NSL + sl) * Qpad + q];
  float s = (s0 + s1) + (s2 + s3);
  float idv = invd[(size_t)n * Qpad + q];
  *(f32x2*)(ic + ((size_t)n * Qpad + q) * 2) = f32x2{idv, -logf(s) - idv};
}

// ---- rowmax, compile-time sizes, branch-free clamped prefetch ----
template<int QREAL, int QPAD, int PPAD>
__device__ __forceinline__ void rowmax_body(
    const __bf16* __restrict__ S, const float* __restrict__ ic,
    float* __restrict__ kmax, int n, int blk, int tid)
{
  constexpr int NQ8 = QREAL >> 3;          // 392 or 98
  constexpr int NIT = (NQ8 + 255) / 256;   // 2 or 1
  int p0 = blk * 8;
  const __bf16* Sp = S + ((size_t)n * PPAD + p0) * QPAD;
  const float* icp = ic + (size_t)n * QPAD * 2;
  float m[8];
#pragma unroll
  for (int r = 0; r < 8; r++) m[r] = -INFINITY;

  bf16x8 sv[NIT][8];
  f32x4 icv[NIT][4];  // 4x f32x4 = 8 (id,c) pairs
  bool valid[NIT];
#pragma unroll
  for (int ii = 0; ii < NIT; ii++) {
    int i = tid + ii * 256;
    valid[ii] = (i < NQ8);
    int ic_ = valid[ii] ? i : tid;  // clamped (safe, redundant) index
#pragma unroll
    for (int r = 0; r < 8; r++)
      sv[ii][r] = __builtin_nontemporal_load((const bf16x8*)(Sp + (size_t)r * QPAD + (size_t)ic_ * 8));
#pragma unroll
    for (int k = 0; k < 4; k++)
      icv[ii][k] = *(const f32x4*)(icp + (size_t)ic_ * 16 + k * 4);
  }
#pragma unroll
  for (int ii = 0; ii < NIT; ii++) {
    float id8[8], c8[8];
#pragma unroll
    for (int k = 0; k < 4; k++) {
      id8[k * 2] = icv[ii][k][0];     c8[k * 2] = icv[ii][k][1];
      id8[k * 2 + 1] = icv[ii][k][2]; c8[k * 2 + 1] = icv[ii][k][3];
    }
    if (!valid[ii])
#pragma unroll
      for (int j = 0; j < 8; j++) c8[j] = -INFINITY;
#pragma unroll
    for (int r = 0; r < 8; r++)
#pragma unroll
      for (int j = 0; j < 8; j++)
        m[r] = fmaxf(m[r], fmaf((float)sv[ii][r][j], id8[j], c8[j]));
  }
#pragma unroll
  for (int r = 0; r < 8; r++)
    for (int off = 32; off > 0; off >>= 1)
      m[r] = fmaxf(m[r], __shfl_xor(m[r], off, 64));
  __shared__ float red[4][8];
  int w = tid >> 6;
  if ((tid & 63) == 0)
    for (int r = 0; r < 8; r++) red[w][r] = m[r];
  __syncthreads();
  if (tid < 8) {
    int r = tid;
    float mr = fmaxf(fmaxf(red[0][r], red[1][r]), fmaxf(red[2][r], red[3][r]));
    kmax[(size_t)n * PPAD + p0 + r] = __expf(mr);
  }
}

// exact 1D grid: 1960 blocks
__global__ __launch_bounds__(256) void rowmax_kernel(
    const __bf16* __restrict__ S3, const float* __restrict__ ic3, float* __restrict__ km3,
    const __bf16* __restrict__ S4, const float* __restrict__ ic4, float* __restrict__ km4)
{
  int id = blockIdx.x;
  if (id < 1568) {
    int n = id / 392, blk = id - n * 392;
    rowmax_body<3136, 3200, 3200>(S3, ic3, km3, n, blk, threadIdx.x);
  } else {
    id -= 1568;
    int n = id / 98, blk = id - n * 98;
    rowmax_body<784, 896, 896>(S4, ic4, km4, n, blk, threadIdx.x);
  }
}

// loss = 0.5 * sum_n -log(mean_p kmax3) + 1.0 * sum_n -log(mean_p kmax4)
__global__ void final_kernel(const float* __restrict__ kmax3, const float* __restrict__ kmax4,
                             float* __restrict__ out)
{
  __shared__ float red[256];
  int tid = threadIdx.x;
  float total = 0.f;
  for (int l = 0; l < 2; l++) {
    const float* km = l ? kmax4 : kmax3;
    int P = l ? 784 : 3136;
    int Ppad = l ? 896 : 3200;
    float wgt = l ? 1.0f : 0.5f;
    for (int n = 0; n < 4; n++) {
      float s = 0.f;
      for (int i = tid; i < P; i += 256) s += km[(size_t)n * Ppad + i];
      red[tid] = s;
      __syncthreads();
      for (int st = 128; st > 0; st >>= 1) {
        if (tid < st) red[tid] += red[tid + st];
        __syncthreads();
      }
      if (tid == 0) total += wgt * (-logf(red[0] / (float)P));
      __syncthreads();
    }
  }
  if (tid == 0) out[0] = total;
}

extern "C" void kernel_launch(void* const* d_in, const int* in_sizes, int n_in,
                              void* d_out, int out_size, void* d_ws, size_t ws_size,
                              hipStream_t stream)
{
  const float* gen3 = (const float*)d_in[0];
  const float* tar3 = (const float*)d_in[1];
  const float* gen4 = (const float*)d_in[2];
  const float* tar4 = (const float*)d_in[3];

  char* ws = (char*)d_ws;
  size_t off = 0;
  auto take = [&](size_t bytes) { char* p = ws + off; off += bytes; return p; };

  __bf16* That3 = (__bf16*)take(6553600);       // 4*3200*256*2
  __bf16* Ghat3 = (__bf16*)take(6553600);
  __bf16* That4 = (__bf16*)take(3670016);       // 4*896*512*2
  __bf16* Ghat4 = (__bf16*)take(3670016);
  __bf16* S3    = (__bf16*)take(81920000);      // 4*3200*3200*2
  __bf16* S4    = (__bf16*)take(6422528);       // 4*896*896*2
  float*  Cm3   = (float*) take(2560000);       // 4*50*3200*4
  float*  Cm4   = (float*) take(200704);        // 4*14*896*4
  float*  Zp3   = (float*) take(5017600);       // 4*98*3200*4
  float*  Zp4   = (float*) take(702464);        // 4*49*896*4
  float* invd3  = (float*)take(51200);
  float* ic3    = (float*)take(102400);         // interleaved (invd,c) 4*3200*8
  float* kmax3  = (float*)take(51200);
  float* invd4  = (float*)take(14336);
  float* ic4    = (float*)take(28672);
  float* kmax4  = (float*)take(14336);

  norm_kernel<<<dim3(1, 100, 8), 256, 0, stream>>>(gen3, tar3, Ghat3, That3,
                                                   gen4, tar4, Ghat4, That4);
  gemm_kernel<<<2696, 256, 0, stream>>>(That3, Ghat3, S3, Cm3,
                                        That4, Ghat4, S4, Cm4);
  invd_kernel<<<dim3(13, 8), 256, 0, stream>>>(Cm3, invd3, Cm4, invd4);
  z_kernel<<<980, 256, 0, stream>>>(S3, invd3, Zp3,
                                    S4, invd4, Zp4);
  reduce_kernel<<<dim3(13, 8), 256, 0, stream>>>(Zp3, invd3, ic3,
                                                 Zp4, invd4, ic4);
  rowmax_kernel<<<1960, 256, 0, stream>>>(S3, ic3, kmax3,
                                          S4, ic4, kmax4);
  final_kernel<<<1, 256, 0, stream>>>(kmax3, kmax4, (float*)d_out);
}